// Round 1
// baseline (973.982 us; speedup 1.0000x reference)
//
#include <hip/hip_runtime.h>
#include <hip/hip_bf16.h>
#include <cstddef>

typedef __hip_bfloat16 bf16;
typedef __attribute__((ext_vector_type(8))) short s16x8;
typedef __attribute__((ext_vector_type(4))) short s16x4;
typedef __attribute__((ext_vector_type(4))) float f32x4;

static constexpr int BATCH = 16;
static constexpr int CH    = 512;    // DIM
static constexpr int NPOS  = 4096;   // h*w
static constexpr int OQKV  = 1536;   // 3*HID
static constexpr int NHEAD = 8;
static constexpr int DHEAD = 64;
#define EPSF 1e-5f
#define QSCALE 0.125f

__device__ __forceinline__ float b2f(bf16 v){ return __bfloat162float(v); }
__device__ __forceinline__ bf16  f2b(float v){ return __float2bfloat16(v); }
__device__ __forceinline__ unsigned short f2bbits(float v){
    bf16 t = __float2bfloat16(v);
    return *reinterpret_cast<unsigned short*>(&t);
}

// ---------------- K0: fp32 -> bf16 convert (weights) ----------------------
__global__ __launch_bounds__(256) void cvt_kernel(
    const float* __restrict__ in, bf16* __restrict__ out, int n)
{
    int i = blockIdx.x * 256 + threadIdx.x;
    if (i < n) out[i] = f2b(in[i]);
}

// ---------------- K1: fused chan-LN + transpose: x[c][p] fp32 -> xt[p][c] bf16
__global__ __launch_bounds__(256) void ln_transpose_kernel(
    const float* __restrict__ x, const float* __restrict__ g, bf16* __restrict__ xt)
{
    __shared__ float red[8][64];
    __shared__ float mean_s[64], rstd_s[64];
    __shared__ unsigned short tile[64][66];   // [p][c], pad 66: 2-way-free LDS
    int tid = threadIdx.x;
    int pl = tid & 63, cg = tid >> 6;
    int p0 = blockIdx.x * 64;
    int b  = blockIdx.y;
    const float* xb = x + (size_t)b * CH * NPOS;
    float s = 0.f, s2 = 0.f;
    for (int c = cg * 128; c < cg * 128 + 128; c++) {
        float v = xb[(size_t)c * NPOS + p0 + pl];
        s += v; s2 += v * v;
    }
    red[cg][pl] = s; red[4 + cg][pl] = s2;
    __syncthreads();
    if (tid < 64) {
        float ts  = red[0][tid] + red[1][tid] + red[2][tid] + red[3][tid];
        float ts2 = red[4][tid] + red[5][tid] + red[6][tid] + red[7][tid];
        float m   = ts * (1.f / CH);
        float var = ts2 * (1.f / CH) - m * m;
        mean_s[tid] = m;
        rstd_s[tid] = rsqrtf(var + EPSF);
    }
    __syncthreads();
    for (int c0 = 0; c0 < CH; c0 += 64) {
        #pragma unroll
        for (int it = 0; it < 16; it++) {
            int cl = it * 4 + cg;
            float v = xb[(size_t)(c0 + cl) * NPOS + p0 + pl];
            tile[pl][cl] = f2bbits((v - mean_s[pl]) * rstd_s[pl] * g[c0 + cl]);
        }
        __syncthreads();
        #pragma unroll
        for (int it = 0; it < 8; it++) {
            int r  = it * 8 + (tid >> 5);
            int cp = tid & 31;
            unsigned v = *(const unsigned*)&tile[r][cp * 2];
            *(unsigned*)(xt + ((size_t)b * NPOS + p0 + r) * CH + c0 + cp * 2) = v;
        }
        __syncthreads();
    }
}

// ---------------- K2/K7: MFMA bf16 GEMM, 256x256 tile, counted-vmcnt pipeline
// C[b][o][p] = sum_k A[o][k] * B[b][n=p][k]  (+bias[o]), K=512 fixed.
// 8 waves (2M x 4N), per-wave output 128x64. LDS chunk-major (conflict-free),
// double-buffered; tile t+1 prefetched during tile t, waited with vmcnt(8).
__global__ __launch_bounds__(512, 2) void mfma_gemm256_kernel(
    const bf16* __restrict__ A, const bf16* __restrict__ B, size_t Bbatch,
    bf16* __restrict__ C, size_t Cbatch, const float* __restrict__ bias)
{
    // chunk-major: slot s (16B = 8 bf16) holds row m = s&255, kchunk c = s>>8
    __shared__ alignas(16) short As[2][16384];
    __shared__ alignas(16) short Bs[2][16384];
    int tid  = threadIdx.x;
    int lane = tid & 63, w = tid >> 6;
    int wr = w >> 2, wc = w & 3;          // 2 x 4 wave grid
    int pT = blockIdx.x * 256;
    int oT = blockIdx.y * 256;
    int b  = blockIdx.z;
    const bf16* Bb = B + (size_t)b * Bbatch;

    f32x4 acc[8][4];
    #pragma unroll
    for (int i = 0; i < 8; i++)
        #pragma unroll
        for (int j = 0; j < 4; j++) acc[i][j] = f32x4{0.f, 0.f, 0.f, 0.f};

    // stage one 256x64 K-tile of A and B into buffer d (8 loads/thread)
    auto stage = [&](int d, int kT) {
        #pragma unroll
        for (int it = 0; it < 4; ++it) {
            int s = it * 512 + tid;
            int m = s & 255, c = s >> 8;
            const bf16* ga = A  + (size_t)(oT + m) * 512 + kT + c * 8;
            const bf16* gb = Bb + (size_t)(pT + m) * 512 + kT + c * 8;
            int sbase = it * 512 + w * 64;   // wave-uniform LDS base
            __builtin_amdgcn_global_load_lds(
                (const __attribute__((address_space(1))) void*)ga,
                (__attribute__((address_space(3))) void*)(&As[d][(size_t)sbase * 8]), 16, 0, 0);
            __builtin_amdgcn_global_load_lds(
                (const __attribute__((address_space(1))) void*)gb,
                (__attribute__((address_space(3))) void*)(&Bs[d][(size_t)sbase * 8]), 16, 0, 0);
        }
    };

    stage(0, 0);
    #pragma unroll 1
    for (int t = 0; t < 8; ++t) {
        int cur = t & 1;
        if (t < 7) {
            stage(cur ^ 1, (t + 1) * 64);
            // tile t (oldest 8 loads) must land; tile t+1's 8 stay in flight
            asm volatile("s_waitcnt vmcnt(8)" ::: "memory");
        } else {
            asm volatile("s_waitcnt vmcnt(0)" ::: "memory");
        }
        __builtin_amdgcn_s_barrier();
        asm volatile("" ::: "memory");

        const s16x8* Av = (const s16x8*)As[cur];
        const s16x8* Bv = (const s16x8*)Bs[cur];
        #pragma unroll
        for (int kk = 0; kk < 2; ++kk) {
            int cbase = kk * 4 + (lane >> 4);
            s16x8 af[8], bfr[4];
            #pragma unroll
            for (int i = 0; i < 8; i++)
                af[i] = Av[cbase * 256 + wr * 128 + i * 16 + (lane & 15)];
            #pragma unroll
            for (int j = 0; j < 4; j++)
                bfr[j] = Bv[cbase * 256 + wc * 64 + j * 16 + (lane & 15)];
            #pragma unroll
            for (int i = 0; i < 8; i++)
                #pragma unroll
                for (int j = 0; j < 4; j++)
                    acc[i][j] = __builtin_amdgcn_mfma_f32_16x16x32_bf16(
                        af[i], bfr[j], acc[i][j], 0, 0, 0);
        }
        asm volatile("" ::: "memory");
        __builtin_amdgcn_s_barrier();
    }

    bf16* Cb = C + (size_t)b * Cbatch;
    #pragma unroll
    for (int i = 0; i < 8; i++) {
        #pragma unroll
        for (int r = 0; r < 4; r++) {
            int o = oT + wr * 128 + i * 16 + (lane >> 4) * 4 + r;
            float bv = bias ? bias[o] : 0.f;
            #pragma unroll
            for (int j = 0; j < 4; j++) {
                int p = pT + wc * 64 + j * 16 + (lane & 15);
                Cb[(size_t)o * NPOS + p] = f2b(acc[i][j][r] + bv);
            }
        }
    }
}

// ---------------- K3: q softmax over d (in place, then *scale) ----------
__global__ __launch_bounds__(256) void q_softmax_kernel(bf16* __restrict__ qkv)
{
    int n = blockIdx.x * 256 + threadIdx.x;
    int m = blockIdx.y, b = blockIdx.z;
    bf16* q = qkv + ((size_t)b * OQKV + m * DHEAD) * NPOS + n;
    float r[DHEAD];
    float mx = -1e30f;
    #pragma unroll
    for (int i = 0; i < DHEAD; i++) { r[i] = b2f(q[(size_t)i * NPOS]); mx = fmaxf(mx, r[i]); }
    float s = 0.f;
    #pragma unroll
    for (int i = 0; i < DHEAD; i++) { r[i] = expf(r[i] - mx); s += r[i]; }
    float inv = QSCALE / s;
    #pragma unroll
    for (int i = 0; i < DHEAD; i++) q[(size_t)i * NPOS] = f2b(r[i] * inv);
}

// ---------------- K4: k softmax over n (in place) -----------------------
__global__ __launch_bounds__(256) void k_softmax_kernel(bf16* __restrict__ qkv)
{
    int d = blockIdx.x, m = blockIdx.y, b = blockIdx.z;
    bf16* row = qkv + ((size_t)b * OQKV + CH + m * DHEAD + d) * NPOS;
    __shared__ float red[256];
    int tid = threadIdx.x;
    float mx = -1e30f;
    for (int i = tid; i < NPOS; i += 256) mx = fmaxf(mx, b2f(row[i]));
    red[tid] = mx; __syncthreads();
    for (int s = 128; s > 0; s >>= 1) { if (tid < s) red[tid] = fmaxf(red[tid], red[tid + s]); __syncthreads(); }
    mx = red[0]; __syncthreads();
    float sum = 0.f;
    for (int i = tid; i < NPOS; i += 256) sum += expf(b2f(row[i]) - mx);
    red[tid] = sum; __syncthreads();
    for (int s = 128; s > 0; s >>= 1) { if (tid < s) red[tid] += red[tid + s]; __syncthreads(); }
    float inv = 1.f / red[0];
    for (int i = tid; i < NPOS; i += 256) row[i] = f2b(expf(b2f(row[i]) - mx) * inv);
}

// ---------------- K5: context partials ctx[i][j] = sum_n k[i,n]*v[j,n] ---
__global__ __launch_bounds__(256) void ctx_gemm_kernel(
    const bf16* __restrict__ qkv, float* __restrict__ ctx)
{
    __shared__ float kt[32][65];
    __shared__ float vt[32][65];
    int tid = threadIdx.x;
    int tx = tid & 15, ty = tid >> 4;
    int split = blockIdx.x;
    int m = blockIdx.y, b = blockIdx.z;
    int nBase = split * (NPOS / 4);
    const bf16* kb = qkv + ((size_t)b * OQKV + CH     + m * DHEAD) * NPOS;
    const bf16* vb = qkv + ((size_t)b * OQKV + 2 * CH + m * DHEAD) * NPOS;
    float acc[4][4] = {};
    for (int nT = nBase; nT < nBase + NPOS / 4; nT += 32) {
        for (int l = tid; l < 64 * 32; l += 256) {
            int r = l >> 5, cc = l & 31;
            kt[cc][r] = b2f(kb[(size_t)r * NPOS + nT + cc]);
            vt[cc][r] = b2f(vb[(size_t)r * NPOS + nT + cc]);
        }
        __syncthreads();
        #pragma unroll
        for (int kk = 0; kk < 32; kk++) {
            float a[4], bb[4];
            #pragma unroll
            for (int i = 0; i < 4; i++) a[i]  = kt[kk][ty * 4 + i];
            #pragma unroll
            for (int j = 0; j < 4; j++) bb[j] = vt[kk][tx * 4 + j];
            #pragma unroll
            for (int i = 0; i < 4; i++)
                #pragma unroll
                for (int j = 0; j < 4; j++) acc[i][j] += a[i] * bb[j];
        }
        __syncthreads();
    }
    float* cb = ctx + ((size_t)split * BATCH * NHEAD + b * NHEAD + m) * (DHEAD * DHEAD);
    #pragma unroll
    for (int i = 0; i < 4; i++)
        #pragma unroll
        for (int j = 0; j < 4; j++)
            cb[(ty * 4 + i) * DHEAD + tx * 4 + j] = acc[i][j];
}

// ---------------- K6: out[j,n]=sum_i ctx[i,j] q[i,n] → v-slot TRANSPOSED [n][hid]
__global__ __launch_bounds__(256) void attn_out_kernel(
    bf16* __restrict__ qkv, const float* __restrict__ ctx)
{
    __shared__ float sc[DHEAD * DHEAD];
    int tid = threadIdx.x;
    int nT = blockIdx.x * 256;
    int m = blockIdx.y, b = blockIdx.z;
    size_t cbase = (size_t)(b * NHEAD + m) * (DHEAD * DHEAD);
    for (int l = tid; l < DHEAD * DHEAD; l += 256) {
        float v = 0.f;
        #pragma unroll
        for (int s = 0; s < 4; s++)
            v += ctx[(size_t)s * BATCH * NHEAD * DHEAD * DHEAD + cbase + l];
        sc[l] = v;
    }
    __syncthreads();
    int n = nT + tid;
    const bf16* q = qkv + ((size_t)b * OQKV + m * DHEAD) * NPOS + n;
    float qr[DHEAD];
    #pragma unroll
    for (int i = 0; i < DHEAD; i++) qr[i] = b2f(q[(size_t)i * NPOS]);
    bf16* ovt = qkv + ((size_t)b * OQKV + 2 * CH) * NPOS + (size_t)n * (CH) + m * DHEAD;
    for (int jb = 0; jb < 16; jb++) {
        s16x4 pack;
        #pragma unroll
        for (int u = 0; u < 4; u++) {
            int j = jb * 4 + u;
            float a = 0.f;
            #pragma unroll
            for (int i = 0; i < DHEAD; i++) a += sc[i * DHEAD + j] * qr[i];
            pack[u] = (short)f2bbits(a);
        }
        *(s16x4*)(ovt + jb * 4) = pack;
    }
}

// ---------------- K8: final channel-LN, k-slot (bf16) → d_out (fp32) -----
__global__ __launch_bounds__(256) void ln_final_kernel(
    const bf16* __restrict__ qkv, const float* __restrict__ g2, float* __restrict__ out)
{
    int g = blockIdx.x * 256 + threadIdx.x;
    int b = g >> 12, p = g & 4095;
    const bf16* xp = qkv + ((size_t)b * OQKV + CH) * NPOS + p;
    float s = 0.f, s2 = 0.f;
    for (int c = 0; c < CH; c++) {
        float v = b2f(xp[(size_t)c * NPOS]);
        s += v; s2 += v * v;
    }
    float m = s * (1.f / CH);
    float var = s2 * (1.f / CH) - m * m;
    float rs = rsqrtf(var + EPSF);
    float* op = out + (size_t)b * CH * NPOS + p;
    for (int c = 0; c < CH; c++) {
        float v = b2f(xp[(size_t)c * NPOS]);
        op[(size_t)c * NPOS] = (v - m) * rs * g2[c];
    }
}

extern "C" void kernel_launch(void* const* d_in, const int* in_sizes, int n_in,
                              void* d_out, int out_size, void* d_ws, size_t ws_size,
                              hipStream_t stream)
{
    const float* x          = (const float*)d_in[0];
    const float* norm_g     = (const float*)d_in[1];
    const float* qkv_w      = (const float*)d_in[2];
    const float* out_w      = (const float*)d_in[3];
    const float* out_b      = (const float*)d_in[4];
    const float* out_norm_g = (const float*)d_in[5];
    float* outp = (float*)d_out;

    char* ws = (char*)d_ws;
    bf16*  qkv = (bf16*)ws;                                  // 201,326,592 B
    bf16*  wqb = (bf16*)(ws + (size_t)201326592);            // 1536*512 bf16
    bf16*  wob = wqb + (size_t)OQKV * CH;                    // 512*512 bf16
    float* ctx = (float*)(wob + (size_t)CH * CH);            // 4*16*8*64*64 f32
    bf16*  xnt = (bf16*)d_out;                               // xn^T [b][p][c] bf16, 64 MB (scratch until final LN)

    // 0. weight conversion
    cvt_kernel<<<dim3((OQKV * CH + 255) / 256), 256, 0, stream>>>(qkv_w, wqb, OQKV * CH);
    cvt_kernel<<<dim3((CH * CH + 255) / 256), 256, 0, stream>>>(out_w, wob, CH * CH);
    // 1. LN + transpose -> xn^T (in d_out scratch)
    ln_transpose_kernel<<<dim3(NPOS / 64, BATCH), 256, 0, stream>>>(x, norm_g, xnt);
    // 2. QKV projection (MFMA 256^2): [1536 x 4096] per batch
    mfma_gemm256_kernel<<<dim3(NPOS / 256, OQKV / 256, BATCH), 512, 0, stream>>>(
        wqb, xnt, (size_t)NPOS * CH, qkv, (size_t)OQKV * NPOS, nullptr);
    // 3. q softmax over d
    q_softmax_kernel<<<dim3(16, NHEAD, BATCH), 256, 0, stream>>>(qkv);
    // 4. k softmax over n
    k_softmax_kernel<<<dim3(DHEAD, NHEAD, BATCH), 256, 0, stream>>>(qkv);
    // 5. context partials
    ctx_gemm_kernel<<<dim3(4, NHEAD, BATCH), 256, 0, stream>>>(qkv, ctx);
    // 6. attention out -> v-slot transposed [n][hid]
    attn_out_kernel<<<dim3(16, NHEAD, BATCH), 256, 0, stream>>>(qkv, ctx);
    // 7. out projection + bias (MFMA 256^2): [512 x 4096] per batch -> k-slot [o][p]
    mfma_gemm256_kernel<<<dim3(NPOS / 256, CH / 256, BATCH), 512, 0, stream>>>(
        wob, qkv + (size_t)2 * CH * NPOS, (size_t)OQKV * NPOS,
        qkv + (size_t)CH * NPOS, (size_t)OQKV * NPOS, out_b);
    // 8. final LN -> d_out (overwrites xnt scratch; xnt dead by now)
    ln_final_kernel<<<dim3(256), 256, 0, stream>>>(qkv, out_norm_g, outp);
}

// Round 2
// 860.288 us; speedup vs baseline: 1.1322x; 1.1322x over previous
//
#include <hip/hip_runtime.h>
#include <hip/hip_bf16.h>
#include <cstddef>

typedef __hip_bfloat16 bf16;
typedef __attribute__((ext_vector_type(8))) short s16x8;
typedef __attribute__((ext_vector_type(4))) short s16x4;
typedef __attribute__((ext_vector_type(4))) float f32x4;

static constexpr int BATCH = 16;
static constexpr int CH    = 512;    // DIM
static constexpr int NPOS  = 4096;   // h*w
static constexpr int OQKV  = 1536;   // 3*HID
static constexpr int NHEAD = 8;
static constexpr int DHEAD = 64;
#define EPSF 1e-5f
#define QSCALE 0.125f

__device__ __forceinline__ float b2f(bf16 v){ return __bfloat162float(v); }
__device__ __forceinline__ bf16  f2b(float v){ return __float2bfloat16(v); }
__device__ __forceinline__ unsigned short f2bbits(float v){
    bf16 t = __float2bfloat16(v);
    return *reinterpret_cast<unsigned short*>(&t);
}
__device__ __forceinline__ float s2f(short s){
    union { unsigned u; float f; } c; c.u = ((unsigned)(unsigned short)s) << 16; return c.f;
}

// ---------------- K0: fp32 -> bf16 convert (weights) ----------------------
__global__ __launch_bounds__(256) void cvt_kernel(
    const float* __restrict__ in, bf16* __restrict__ out, int n)
{
    int i = blockIdx.x * 256 + threadIdx.x;
    if (i < n) out[i] = f2b(in[i]);
}

// ---------------- K1: fused chan-LN + transpose: x[c][p] fp32 -> xt[p][c] bf16
__global__ __launch_bounds__(256) void ln_transpose_kernel(
    const float* __restrict__ x, const float* __restrict__ g, bf16* __restrict__ xt)
{
    __shared__ float red[8][64];
    __shared__ float mean_s[64], rstd_s[64];
    __shared__ unsigned short tile[64][66];   // [p][c], pad 66: 2-way-free LDS
    int tid = threadIdx.x;
    int pl = tid & 63, cg = tid >> 6;
    int p0 = blockIdx.x * 64;
    int b  = blockIdx.y;
    const float* xb = x + (size_t)b * CH * NPOS;
    float s = 0.f, s2 = 0.f;
    for (int c = cg * 128; c < cg * 128 + 128; c++) {
        float v = xb[(size_t)c * NPOS + p0 + pl];
        s += v; s2 += v * v;
    }
    red[cg][pl] = s; red[4 + cg][pl] = s2;
    __syncthreads();
    if (tid < 64) {
        float ts  = red[0][tid] + red[1][tid] + red[2][tid] + red[3][tid];
        float ts2 = red[4][tid] + red[5][tid] + red[6][tid] + red[7][tid];
        float m   = ts * (1.f / CH);
        float var = ts2 * (1.f / CH) - m * m;
        mean_s[tid] = m;
        rstd_s[tid] = rsqrtf(var + EPSF);
    }
    __syncthreads();
    for (int c0 = 0; c0 < CH; c0 += 64) {
        #pragma unroll
        for (int it = 0; it < 16; it++) {
            int cl = it * 4 + cg;
            float v = xb[(size_t)(c0 + cl) * NPOS + p0 + pl];
            tile[pl][cl] = f2bbits((v - mean_s[pl]) * rstd_s[pl] * g[c0 + cl]);
        }
        __syncthreads();
        #pragma unroll
        for (int it = 0; it < 8; it++) {
            int r  = it * 8 + (tid >> 5);
            int cp = tid & 31;
            unsigned v = *(const unsigned*)&tile[r][cp * 2];
            *(unsigned*)(xt + ((size_t)b * NPOS + p0 + r) * CH + c0 + cp * 2) = v;
        }
        __syncthreads();
    }
}

// ---------------- K2/K7: MFMA bf16 GEMM, 256x256 tile, 8-phase schedule ---
// C[b][o][p] = sum_k A[o][k] * B[b][n=p][k]  (+bias[o]), K=512 fixed.
// 8 waves (2M x 4N), per-wave output 128x64. LDS chunk-major (conflict-free,
// measured 0 bank conflicts), double-buffered. Per K-tile: 4 phases, each
// {ds_read subtile || stage 1/4 of next tile -> barrier -> lgkmcnt(0) ->
// setprio(1) 16xMFMA setprio(0) -> barrier}; counted vmcnt(2) once per
// K-tile at the buffer swap (never drained to 0 in the main loop).
__global__ __launch_bounds__(512, 2) void mfma_gemm256_kernel(
    const bf16* __restrict__ A, const bf16* __restrict__ B, size_t Bbatch,
    bf16* __restrict__ C, size_t Cbatch, const float* __restrict__ bias)
{
    // chunk-major: slot s (16B = 8 bf16) holds row m = s&255, kchunk c = s>>8
    __shared__ alignas(16) short As[2][16384];
    __shared__ alignas(16) short Bs[2][16384];
    int tid  = threadIdx.x;
    int lane = tid & 63, w = tid >> 6;
    int wr = w >> 2, wc = w & 3;          // 2 x 4 wave grid
    int pT = blockIdx.x * 256;
    int oT = blockIdx.y * 256;
    int b  = blockIdx.z;
    const bf16* Bb = B + (size_t)b * Bbatch;

    f32x4 acc[8][4];
    #pragma unroll
    for (int i = 0; i < 8; i++)
        #pragma unroll
        for (int j = 0; j < 4; j++) acc[i][j] = f32x4{0.f, 0.f, 0.f, 0.f};

    // stage quarter q of a 256x64 K-tile (A and B) into buffer d: 2 gload_lds
    auto stageQ = [&](int d, int kT, int q) {
        int s = q * 512 + tid;
        int m = s & 255, c = s >> 8;
        const bf16* ga = A  + (size_t)(oT + m) * 512 + kT + c * 8;
        const bf16* gb = Bb + (size_t)(pT + m) * 512 + kT + c * 8;
        int sbase = q * 512 + w * 64;   // wave-uniform LDS base, lane l -> slot sbase+l
        __builtin_amdgcn_global_load_lds(
            (const __attribute__((address_space(1))) void*)ga,
            (__attribute__((address_space(3))) void*)(&As[d][(size_t)sbase * 8]), 16, 0, 0);
        __builtin_amdgcn_global_load_lds(
            (const __attribute__((address_space(1))) void*)gb,
            (__attribute__((address_space(3))) void*)(&Bs[d][(size_t)sbase * 8]), 16, 0, 0);
    };

    // prologue: full tile 0 into buffer 0 (8 loads/thread in flight)
    #pragma unroll
    for (int q = 0; q < 4; ++q) stageQ(0, 0, q);

    #pragma unroll 1
    for (int t = 0; t < 8; ++t) {
        int cur = t & 1;
        const s16x8* Av = (const s16x8*)As[cur];
        const s16x8* Bv = (const s16x8*)Bs[cur];
        s16x8 bfr[4];
        #pragma unroll
        for (int q = 0; q < 4; ++q) {
            const int kk = q >> 1, ih = q & 1;
            int cbase = kk * 4 + (lane >> 4);
            if (q == 0) {
                // buffer-swap boundary: issue next tile's first quarter, then
                // counted wait -> all of tile t landed, 2 newest stay in flight
                if (t < 7) {
                    stageQ(cur ^ 1, (t + 1) * 64, 0);
                    asm volatile("s_waitcnt vmcnt(2)" ::: "memory");
                } else {
                    asm volatile("s_waitcnt vmcnt(0)" ::: "memory");
                }
                __builtin_amdgcn_s_barrier();
                asm volatile("" ::: "memory");   // keep ds_reads below the barrier
            }
            s16x8 af[4];
            #pragma unroll
            for (int i = 0; i < 4; i++)
                af[i] = Av[cbase * 256 + wr * 128 + (ih * 4 + i) * 16 + (lane & 15)];
            if (ih == 0) {
                #pragma unroll
                for (int j = 0; j < 4; j++)
                    bfr[j] = Bv[cbase * 256 + wc * 64 + j * 16 + (lane & 15)];
            }
            if (q != 0) {
                if (t < 7) stageQ(cur ^ 1, (t + 1) * 64, q);
                __builtin_amdgcn_s_barrier();
            }
            asm volatile("s_waitcnt lgkmcnt(0)" ::: "memory");
            __builtin_amdgcn_sched_barrier(0);   // rule #18: pin MFMA below the wait
            __builtin_amdgcn_s_setprio(1);
            #pragma unroll
            for (int i = 0; i < 4; i++)
                #pragma unroll
                for (int j = 0; j < 4; j++)
                    acc[ih * 4 + i][j] = __builtin_amdgcn_mfma_f32_16x16x32_bf16(
                        af[i], bfr[j], acc[ih * 4 + i][j], 0, 0, 0);
            __builtin_amdgcn_s_setprio(0);
            __builtin_amdgcn_sched_barrier(0);
            __builtin_amdgcn_s_barrier();
        }
    }

    bf16* Cb = C + (size_t)b * Cbatch;
    #pragma unroll
    for (int i = 0; i < 8; i++) {
        #pragma unroll
        for (int r = 0; r < 4; r++) {
            int o = oT + wr * 128 + i * 16 + (lane >> 4) * 4 + r;
            float bv = bias ? bias[o] : 0.f;
            #pragma unroll
            for (int j = 0; j < 4; j++) {
                int p = pT + wc * 64 + j * 16 + (lane & 15);
                Cb[(size_t)o * NPOS + p] = f2b(acc[i][j][r] + bv);
            }
        }
    }
}

// ---------------- K4: k softmax over n, single-read (16 vals/thread) -----
__global__ __launch_bounds__(256) void k_softmax_kernel(bf16* __restrict__ qkv)
{
    int d = blockIdx.x, m = blockIdx.y, b = blockIdx.z;
    bf16* row = qkv + ((size_t)b * OQKV + CH + m * DHEAD + d) * NPOS;
    __shared__ float red[256];
    int tid = threadIdx.x;
    s16x8 v0 = *(const s16x8*)(row + tid * 16);
    s16x8 v1 = *(const s16x8*)(row + tid * 16 + 8);
    float r[16];
    #pragma unroll
    for (int u = 0; u < 8; u++) { r[u] = s2f(v0[u]); r[8 + u] = s2f(v1[u]); }
    float mx = -1e30f;
    #pragma unroll
    for (int u = 0; u < 16; u++) mx = fmaxf(mx, r[u]);
    red[tid] = mx; __syncthreads();
    for (int s = 128; s > 0; s >>= 1) { if (tid < s) red[tid] = fmaxf(red[tid], red[tid + s]); __syncthreads(); }
    mx = red[0]; __syncthreads();
    float sum = 0.f;
    #pragma unroll
    for (int u = 0; u < 16; u++) { r[u] = expf(r[u] - mx); sum += r[u]; }
    red[tid] = sum; __syncthreads();
    for (int s = 128; s > 0; s >>= 1) { if (tid < s) red[tid] += red[tid + s]; __syncthreads(); }
    float inv = 1.f / red[0];
    s16x8 o0, o1;
    #pragma unroll
    for (int u = 0; u < 8; u++) {
        o0[u] = (short)f2bbits(r[u] * inv);
        o1[u] = (short)f2bbits(r[8 + u] * inv);
    }
    *(s16x8*)(row + tid * 16)     = o0;
    *(s16x8*)(row + tid * 16 + 8) = o1;
}

// ---------------- K5: context partials ctx[i][j] = sum_n k[i,n]*v[j,n] ---
__global__ __launch_bounds__(256) void ctx_gemm_kernel(
    const bf16* __restrict__ qkv, float* __restrict__ ctx)
{
    __shared__ float kt[32][65];
    __shared__ float vt[32][65];
    int tid = threadIdx.x;
    int tx = tid & 15, ty = tid >> 4;
    int split = blockIdx.x;
    int m = blockIdx.y, b = blockIdx.z;
    int nBase = split * (NPOS / 4);
    const bf16* kb = qkv + ((size_t)b * OQKV + CH     + m * DHEAD) * NPOS;
    const bf16* vb = qkv + ((size_t)b * OQKV + 2 * CH + m * DHEAD) * NPOS;
    float acc[4][4] = {};
    for (int nT = nBase; nT < nBase + NPOS / 4; nT += 32) {
        for (int l = tid; l < 64 * 32; l += 256) {
            int r = l >> 5, cc = l & 31;
            kt[cc][r] = b2f(kb[(size_t)r * NPOS + nT + cc]);
            vt[cc][r] = b2f(vb[(size_t)r * NPOS + nT + cc]);
        }
        __syncthreads();
        #pragma unroll
        for (int kk = 0; kk < 32; kk++) {
            float a[4], bb[4];
            #pragma unroll
            for (int i = 0; i < 4; i++) a[i]  = kt[kk][ty * 4 + i];
            #pragma unroll
            for (int j = 0; j < 4; j++) bb[j] = vt[kk][tx * 4 + j];
            #pragma unroll
            for (int i = 0; i < 4; i++)
                #pragma unroll
                for (int j = 0; j < 4; j++) acc[i][j] += a[i] * bb[j];
        }
        __syncthreads();
    }
    float* cb = ctx + ((size_t)split * BATCH * NHEAD + b * NHEAD + m) * (DHEAD * DHEAD);
    #pragma unroll
    for (int i = 0; i < 4; i++)
        #pragma unroll
        for (int j = 0; j < 4; j++)
            cb[(ty * 4 + i) * DHEAD + tx * 4 + j] = acc[i][j];
}

// ---------------- K6: fused q-softmax + out[j,n]=sum_i ctx[i,j] q~[i,n]
//                  -> v-slot TRANSPOSED [n][hid]
__global__ __launch_bounds__(256) void attn_out_kernel(
    bf16* __restrict__ qkv, const float* __restrict__ ctx)
{
    __shared__ float sc[DHEAD * DHEAD];
    int tid = threadIdx.x;
    int nT = blockIdx.x * 256;
    int m = blockIdx.y, b = blockIdx.z;
    size_t cbase = (size_t)(b * NHEAD + m) * (DHEAD * DHEAD);
    for (int l = tid; l < DHEAD * DHEAD; l += 256) {
        float v = 0.f;
        #pragma unroll
        for (int s = 0; s < 4; s++)
            v += ctx[(size_t)s * BATCH * NHEAD * DHEAD * DHEAD + cbase + l];
        sc[l] = v;
    }
    __syncthreads();
    int n = nT + tid;
    const bf16* q = qkv + ((size_t)b * OQKV + m * DHEAD) * NPOS + n;  // RAW q
    float qr[DHEAD];
    float mx = -1e30f;
    #pragma unroll
    for (int i = 0; i < DHEAD; i++) { qr[i] = b2f(q[(size_t)i * NPOS]); mx = fmaxf(mx, qr[i]); }
    float s = 0.f;
    #pragma unroll
    for (int i = 0; i < DHEAD; i++) { qr[i] = expf(qr[i] - mx); s += qr[i]; }
    float inv = QSCALE / s;
    #pragma unroll
    for (int i = 0; i < DHEAD; i++) qr[i] *= inv;
    bf16* ovt = qkv + ((size_t)b * OQKV + 2 * CH) * NPOS + (size_t)n * (CH) + m * DHEAD;
    for (int jb = 0; jb < 16; jb++) {
        s16x4 pack;
        #pragma unroll
        for (int u = 0; u < 4; u++) {
            int j = jb * 4 + u;
            float a = 0.f;
            #pragma unroll
            for (int i = 0; i < DHEAD; i++) a += sc[i * DHEAD + j] * qr[i];
            pack[u] = (short)f2bbits(a);
        }
        *(s16x4*)(ovt + jb * 4) = pack;
    }
}

// ---------------- K8: final channel-LN, k-slot (bf16) → d_out (fp32) -----
__global__ __launch_bounds__(256) void ln_final_kernel(
    const bf16* __restrict__ qkv, const float* __restrict__ g2, float* __restrict__ out)
{
    int g = blockIdx.x * 256 + threadIdx.x;
    int b = g >> 12, p = g & 4095;
    const bf16* xp = qkv + ((size_t)b * OQKV + CH) * NPOS + p;
    float s = 0.f, s2 = 0.f;
    for (int c = 0; c < CH; c++) {
        float v = b2f(xp[(size_t)c * NPOS]);
        s += v; s2 += v * v;
    }
    float m = s * (1.f / CH);
    float var = s2 * (1.f / CH) - m * m;
    float rs = rsqrtf(var + EPSF);
    float* op = out + (size_t)b * CH * NPOS + p;
    for (int c = 0; c < CH; c++) {
        float v = b2f(xp[(size_t)c * NPOS]);
        op[(size_t)c * NPOS] = (v - m) * rs * g2[c];
    }
}

extern "C" void kernel_launch(void* const* d_in, const int* in_sizes, int n_in,
                              void* d_out, int out_size, void* d_ws, size_t ws_size,
                              hipStream_t stream)
{
    const float* x          = (const float*)d_in[0];
    const float* norm_g     = (const float*)d_in[1];
    const float* qkv_w      = (const float*)d_in[2];
    const float* out_w      = (const float*)d_in[3];
    const float* out_b      = (const float*)d_in[4];
    const float* out_norm_g = (const float*)d_in[5];
    float* outp = (float*)d_out;

    char* ws = (char*)d_ws;
    bf16*  qkv = (bf16*)ws;                                  // 201,326,592 B
    bf16*  wqb = (bf16*)(ws + (size_t)201326592);            // 1536*512 bf16
    bf16*  wob = wqb + (size_t)OQKV * CH;                    // 512*512 bf16
    float* ctx = (float*)(wob + (size_t)CH * CH);            // 4*16*8*64*64 f32
    bf16*  xnt = (bf16*)d_out;                               // xn^T [b][p][c] bf16, 64 MB (scratch until final LN)

    // 0. weight conversion
    cvt_kernel<<<dim3((OQKV * CH + 255) / 256), 256, 0, stream>>>(qkv_w, wqb, OQKV * CH);
    cvt_kernel<<<dim3((CH * CH + 255) / 256), 256, 0, stream>>>(out_w, wob, CH * CH);
    // 1. LN + transpose -> xn^T (in d_out scratch)
    ln_transpose_kernel<<<dim3(NPOS / 64, BATCH), 256, 0, stream>>>(x, norm_g, xnt);
    // 2. QKV projection (MFMA 256^2, 8-phase): [1536 x 4096] per batch
    mfma_gemm256_kernel<<<dim3(NPOS / 256, OQKV / 256, BATCH), 512, 0, stream>>>(
        wqb, xnt, (size_t)NPOS * CH, qkv, (size_t)OQKV * NPOS, nullptr);
    // 3. k softmax over n (q softmax is fused into attn_out)
    k_softmax_kernel<<<dim3(DHEAD, NHEAD, BATCH), 256, 0, stream>>>(qkv);
    // 4. context partials
    ctx_gemm_kernel<<<dim3(4, NHEAD, BATCH), 256, 0, stream>>>(qkv, ctx);
    // 5. attention out (incl. q softmax) -> v-slot transposed [n][hid]
    attn_out_kernel<<<dim3(16, NHEAD, BATCH), 256, 0, stream>>>(qkv, ctx);
    // 6. out projection + bias (MFMA 256^2, 8-phase) -> k-slot [o][p]
    mfma_gemm256_kernel<<<dim3(NPOS / 256, CH / 256, BATCH), 512, 0, stream>>>(
        wob, qkv + (size_t)2 * CH * NPOS, (size_t)OQKV * NPOS,
        qkv + (size_t)CH * NPOS, (size_t)OQKV * NPOS, out_b);
    // 7. final LN -> d_out (overwrites xnt scratch; xnt dead by now)
    ln_final_kernel<<<dim3(256), 256, 0, stream>>>(qkv, out_norm_g, outp);
}

// Round 3
// 851.358 us; speedup vs baseline: 1.1440x; 1.0105x over previous
//
#include <hip/hip_runtime.h>
#include <hip/hip_bf16.h>
#include <cstddef>

typedef __hip_bfloat16 bf16;
typedef __attribute__((ext_vector_type(8))) short s16x8;
typedef __attribute__((ext_vector_type(4))) short s16x4;
typedef __attribute__((ext_vector_type(4))) float f32x4;

static constexpr int BATCH = 16;
static constexpr int CH    = 512;    // DIM
static constexpr int NPOS  = 4096;   // h*w
static constexpr int OQKV  = 1536;   // 3*HID
static constexpr int NHEAD = 8;
static constexpr int DHEAD = 64;
#define EPSF 1e-5f
#define QSCALE 0.125f

__device__ __forceinline__ float b2f(bf16 v){ return __bfloat162float(v); }
__device__ __forceinline__ bf16  f2b(float v){ return __float2bfloat16(v); }
__device__ __forceinline__ unsigned short f2bbits(float v){
    bf16 t = __float2bfloat16(v);
    return *reinterpret_cast<unsigned short*>(&t);
}
__device__ __forceinline__ float s2f(short s){
    union { unsigned u; float f; } c; c.u = ((unsigned)(unsigned short)s) << 16; return c.f;
}

// ---------------- K0: fp32 -> bf16 convert (weights) ----------------------
__global__ __launch_bounds__(256) void cvt_kernel(
    const float* __restrict__ in, bf16* __restrict__ out, int n)
{
    int i = blockIdx.x * 256 + threadIdx.x;
    if (i < n) out[i] = f2b(in[i]);
}

// ---------------- K1: fused chan-LN + transpose, SINGLE x read ------------
// block = 256 thr, 32 positions x 512 channels. Read x[c][p] fp32 once
// (stats from registers, bf16 staged in LDS), write xt[p][c] bf16 rows
// via b128 stores. LDS pad 35 shorts: transpose gather conflict-free.
__global__ __launch_bounds__(256) void ln_transpose_kernel(
    const float* __restrict__ x, const float* __restrict__ g, bf16* __restrict__ xt)
{
    __shared__ unsigned short st[512][35];   // [c][p]
    __shared__ float red[16][32];
    __shared__ float sm[32], sr[32];
    __shared__ float gl[512];
    int tid = threadIdx.x;
    int p0 = blockIdx.x * 32, b = blockIdx.y;
    int pl = tid & 31, gq = tid >> 5;        // 8 channel-groups
    const float* xb = x + (size_t)b * CH * NPOS + p0;
    for (int i = tid; i < 512; i += 256) gl[i] = g[i];
    float s = 0.f, s2 = 0.f;
    #pragma unroll
    for (int it = 0; it < 64; it++) {
        int c = it * 8 + gq;
        float v = xb[(size_t)c * NPOS + pl];
        s += v; s2 += v * v;
        st[c][pl] = f2bbits(v);
    }
    red[gq][pl] = s; red[8 + gq][pl] = s2;
    __syncthreads();
    if (tid < 32) {
        float ts = 0.f, ts2 = 0.f;
        #pragma unroll
        for (int u = 0; u < 8; u++) { ts += red[u][tid]; ts2 += red[8 + u][tid]; }
        float m   = ts * (1.f / CH);
        float var = ts2 * (1.f / CH) - m * m;
        sm[tid] = m;
        sr[tid] = rsqrtf(var + EPSF);
    }
    __syncthreads();
    // write phase: row r = p0 + (tid>>3); thread covers c = i2*64 + (tid&7)*8 + u
    int r = tid >> 3, cl = tid & 7;
    float m = sm[r], rs = sr[r];
    bf16* orow = xt + ((size_t)b * NPOS + p0 + r) * CH;
    #pragma unroll
    for (int i2 = 0; i2 < 8; i2++) {
        s16x8 pk;
        #pragma unroll
        for (int u = 0; u < 8; u++) {
            int c = i2 * 64 + cl * 8 + u;
            float v = s2f((short)st[c][r]);
            pk[u] = (short)f2bbits((v - m) * rs * gl[c]);
        }
        *(s16x8*)(orow + i2 * 64 + cl * 8) = pk;
    }
}

// ---------------- K2/K7: persistent MFMA bf16 GEMM, 256x256 tiles ---------
// C[b][o][p] = sum_k A[o][k] * B[b][n=p][k] (+bias[o]), K=512.
// grid = 256 blocks exactly (1/CU); each block walks NOB tiles as ONE flat
// K-loop of NOB*8 steps: the double-buffer + counted-vmcnt pipeline rolls
// across output-tile boundaries (last K-step of tile j prefetches tile j+1's
// first K-tile). One cold prologue per CU; stores overlap next tile's loads.
template<int NOB>
__global__ __launch_bounds__(512, 2) void mfma_gemm256p_kernel(
    const bf16* __restrict__ A, const bf16* __restrict__ B, size_t Bbatch,
    bf16* __restrict__ C, size_t Cbatch, const float* __restrict__ bias)
{
    // chunk-major: slot s (16B = 8 bf16) holds row m = s&255, kchunk c = s>>8
    __shared__ alignas(16) short As[2][16384];
    __shared__ alignas(16) short Bs[2][16384];
    constexpr int NSTEPS = NOB * 8;     // tiles-per-block == NOB (16*16/256==1)
    int tid  = threadIdx.x;
    int lane = tid & 63, w = tid >> 6;
    int wr = w >> 2, wc = w & 3;        // 2 x 4 wave grid
    int bid = blockIdx.x;

    f32x4 acc[8][4];
    #pragma unroll
    for (int i = 0; i < 8; i++)
        #pragma unroll
        for (int j = 0; j < 4; j++) acc[i][j] = f32x4{0.f, 0.f, 0.f, 0.f};

    // decode flat step -> tile panel pointers (L = pT + 16*(oB + NOB*b))
    auto decode = [&](int step, const bf16*& Ab, const bf16*& Bp,
                      int& oT, int& pT, int& b) {
        int L  = bid * NOB + (step >> 3);
        pT     = (L & 15) * 256;
        int rem = L >> 4;
        int oB  = rem % NOB;
        b       = rem / NOB;
        oT      = oB * 256;
        Ab = A + (size_t)oT * 512;
        Bp = B + (size_t)b * Bbatch + (size_t)pT * 512;
    };

    // stage quarter q of step's 256x64 K-tile (A and B) into buffer d
    auto stageQ = [&](int d, const bf16* Ab, const bf16* Bp, int kT, int q) {
        int s = q * 512 + tid;
        int m = s & 255, c = s >> 8;
        const bf16* ga = Ab + (size_t)m * 512 + kT + c * 8;
        const bf16* gb = Bp + (size_t)m * 512 + kT + c * 8;
        int sbase = q * 512 + w * 64;   // wave-uniform LDS base
        __builtin_amdgcn_global_load_lds(
            (const __attribute__((address_space(1))) void*)ga,
            (__attribute__((address_space(3))) void*)(&As[d][(size_t)sbase * 8]), 16, 0, 0);
        __builtin_amdgcn_global_load_lds(
            (const __attribute__((address_space(1))) void*)gb,
            (__attribute__((address_space(3))) void*)(&Bs[d][(size_t)sbase * 8]), 16, 0, 0);
    };

    // prologue: step 0 fully into buffer 0
    {
        const bf16 *A0, *B0; int o_, p_, b_;
        decode(0, A0, B0, o_, p_, b_);
        #pragma unroll
        for (int q = 0; q < 4; ++q) stageQ(0, A0, B0, 0, q);
    }

    #pragma unroll 1
    for (int s = 0; s < NSTEPS; ++s) {
        int cur = s & 1;
        bool hn = (s + 1) < NSTEPS;
        const bf16 *An = nullptr, *Bn = nullptr; int ktn = 0;
        if (hn) {
            int o_, p_, b_;
            decode(s + 1, An, Bn, o_, p_, b_);
            ktn = ((s + 1) & 7) * 64;
        }
        const s16x8* Av = (const s16x8*)As[cur];
        const s16x8* Bv = (const s16x8*)Bs[cur];
        s16x8 bfr[4];
        #pragma unroll
        for (int q = 0; q < 4; ++q) {
            const int kk = q >> 1, ih = q & 1;
            int cbase = kk * 4 + (lane >> 4);
            if (q == 0) {
                if (hn) {
                    stageQ(cur ^ 1, An, Bn, ktn, 0);
                    asm volatile("s_waitcnt vmcnt(2)" ::: "memory");
                } else {
                    asm volatile("s_waitcnt vmcnt(0)" ::: "memory");
                }
                __builtin_amdgcn_s_barrier();
                asm volatile("" ::: "memory");
            }
            s16x8 af[4];
            #pragma unroll
            for (int i = 0; i < 4; i++)
                af[i] = Av[cbase * 256 + wr * 128 + (ih * 4 + i) * 16 + (lane & 15)];
            if (ih == 0) {
                #pragma unroll
                for (int j = 0; j < 4; j++)
                    bfr[j] = Bv[cbase * 256 + wc * 64 + j * 16 + (lane & 15)];
            }
            if (q != 0) {
                if (hn) stageQ(cur ^ 1, An, Bn, ktn, q);
                __builtin_amdgcn_s_barrier();
            }
            asm volatile("s_waitcnt lgkmcnt(0)" ::: "memory");
            __builtin_amdgcn_sched_barrier(0);   // pin MFMA below the wait
            __builtin_amdgcn_s_setprio(1);
            #pragma unroll
            for (int i = 0; i < 4; i++)
                #pragma unroll
                for (int j = 0; j < 4; j++)
                    acc[ih * 4 + i][j] = __builtin_amdgcn_mfma_f32_16x16x32_bf16(
                        af[i], bfr[j], acc[ih * 4 + i][j], 0, 0, 0);
            __builtin_amdgcn_s_setprio(0);
            __builtin_amdgcn_sched_barrier(0);
            __builtin_amdgcn_s_barrier();
        }
        if ((s & 7) == 7) {
            // tile epilogue: write C, zero acc. Stores overlap next tile's
            // in-flight loads (drained by the next counted vmcnt).
            const bf16 *d1, *d2; int oT, pT, b;
            decode(s, d1, d2, oT, pT, b);
            bf16* Cb = C + (size_t)b * Cbatch;
            #pragma unroll
            for (int i = 0; i < 8; i++) {
                #pragma unroll
                for (int r = 0; r < 4; r++) {
                    int o = oT + wr * 128 + i * 16 + (lane >> 4) * 4 + r;
                    float bv = bias ? bias[o] : 0.f;
                    #pragma unroll
                    for (int j = 0; j < 4; j++) {
                        int p = pT + wc * 64 + j * 16 + (lane & 15);
                        Cb[(size_t)o * NPOS + p] = f2b(acc[i][j][r] + bv);
                    }
                }
            }
            #pragma unroll
            for (int i = 0; i < 8; i++)
                #pragma unroll
                for (int j = 0; j < 4; j++) acc[i][j] = f32x4{0.f, 0.f, 0.f, 0.f};
        }
    }
}

// ---------------- K4: k softmax STATS only (max, 1/sum) over n ------------
// Normalized k is consumed only by ctx_gemm -> never materialize it.
__global__ __launch_bounds__(256) void k_stats_kernel(
    const bf16* __restrict__ qkv, float2* __restrict__ kstat)
{
    int d = blockIdx.x, m = blockIdx.y, b = blockIdx.z;
    const bf16* row = qkv + ((size_t)b * OQKV + CH + m * DHEAD + d) * NPOS;
    __shared__ float red[256];
    int tid = threadIdx.x;
    s16x8 v0 = *(const s16x8*)(row + tid * 16);
    s16x8 v1 = *(const s16x8*)(row + tid * 16 + 8);
    float r[16];
    #pragma unroll
    for (int u = 0; u < 8; u++) { r[u] = s2f(v0[u]); r[8 + u] = s2f(v1[u]); }
    float mx = -1e30f;
    #pragma unroll
    for (int u = 0; u < 16; u++) mx = fmaxf(mx, r[u]);
    red[tid] = mx; __syncthreads();
    for (int s = 128; s > 0; s >>= 1) { if (tid < s) red[tid] = fmaxf(red[tid], red[tid + s]); __syncthreads(); }
    mx = red[0]; __syncthreads();
    float sum = 0.f;
    #pragma unroll
    for (int u = 0; u < 16; u++) sum += expf(r[u] - mx);
    red[tid] = sum; __syncthreads();
    for (int s = 128; s > 0; s >>= 1) { if (tid < s) red[tid] += red[tid + s]; __syncthreads(); }
    if (tid == 0) {
        float2 st; st.x = mx; st.y = 1.f / red[0];
        kstat[((size_t)b * NHEAD + m) * DHEAD + d] = st;
    }
}

// ---------------- K5: context partials, k-softmax applied on the fly ------
__global__ __launch_bounds__(256) void ctx_gemm_kernel(
    const bf16* __restrict__ qkv, const float2* __restrict__ kstat,
    float* __restrict__ ctx)
{
    __shared__ float kt[32][65];
    __shared__ float vt[32][65];
    __shared__ float smx[64], sinv[64];
    int tid = threadIdx.x;
    int tx = tid & 15, ty = tid >> 4;
    int split = blockIdx.x;
    int m = blockIdx.y, b = blockIdx.z;
    int nBase = split * (NPOS / 4);
    const bf16* kb = qkv + ((size_t)b * OQKV + CH     + m * DHEAD) * NPOS;
    const bf16* vb = qkv + ((size_t)b * OQKV + 2 * CH + m * DHEAD) * NPOS;
    if (tid < 64) {
        float2 st = kstat[((size_t)b * NHEAD + m) * DHEAD + tid];
        smx[tid] = st.x; sinv[tid] = st.y;
    }
    __syncthreads();
    float acc[4][4] = {};
    for (int nT = nBase; nT < nBase + NPOS / 4; nT += 32) {
        for (int l = tid; l < 64 * 32; l += 256) {
            int r = l >> 5, cc = l & 31;
            kt[cc][r] = expf(b2f(kb[(size_t)r * NPOS + nT + cc]) - smx[r]) * sinv[r];
            vt[cc][r] = b2f(vb[(size_t)r * NPOS + nT + cc]);
        }
        __syncthreads();
        #pragma unroll
        for (int kk = 0; kk < 32; kk++) {
            float a[4], bb[4];
            #pragma unroll
            for (int i = 0; i < 4; i++) a[i]  = kt[kk][ty * 4 + i];
            #pragma unroll
            for (int j = 0; j < 4; j++) bb[j] = vt[kk][tx * 4 + j];
            #pragma unroll
            for (int i = 0; i < 4; i++)
                #pragma unroll
                for (int j = 0; j < 4; j++) acc[i][j] += a[i] * bb[j];
        }
        __syncthreads();
    }
    float* cb = ctx + ((size_t)split * BATCH * NHEAD + b * NHEAD + m) * (DHEAD * DHEAD);
    #pragma unroll
    for (int i = 0; i < 4; i++)
        #pragma unroll
        for (int j = 0; j < 4; j++)
            cb[(ty * 4 + i) * DHEAD + tx * 4 + j] = acc[i][j];
}

// ---------------- K6: fused q-softmax + out[j,n]=sum_i ctx[i,j] q~[i,n]
//                  -> v-slot TRANSPOSED [n][hid]
__global__ __launch_bounds__(256) void attn_out_kernel(
    bf16* __restrict__ qkv, const float* __restrict__ ctx)
{
    __shared__ float sc[DHEAD * DHEAD];
    int tid = threadIdx.x;
    int nT = blockIdx.x * 256;
    int m = blockIdx.y, b = blockIdx.z;
    size_t cbase = (size_t)(b * NHEAD + m) * (DHEAD * DHEAD);
    for (int l = tid; l < DHEAD * DHEAD; l += 256) {
        float v = 0.f;
        #pragma unroll
        for (int s = 0; s < 4; s++)
            v += ctx[(size_t)s * BATCH * NHEAD * DHEAD * DHEAD + cbase + l];
        sc[l] = v;
    }
    __syncthreads();
    int n = nT + tid;
    const bf16* q = qkv + ((size_t)b * OQKV + m * DHEAD) * NPOS + n;  // RAW q
    float qr[DHEAD];
    float mx = -1e30f;
    #pragma unroll
    for (int i = 0; i < DHEAD; i++) { qr[i] = b2f(q[(size_t)i * NPOS]); mx = fmaxf(mx, qr[i]); }
    float s = 0.f;
    #pragma unroll
    for (int i = 0; i < DHEAD; i++) { qr[i] = expf(qr[i] - mx); s += qr[i]; }
    float inv = QSCALE / s;
    #pragma unroll
    for (int i = 0; i < DHEAD; i++) qr[i] *= inv;
    bf16* ovt = qkv + ((size_t)b * OQKV + 2 * CH) * NPOS + (size_t)n * (CH) + m * DHEAD;
    for (int jb = 0; jb < 16; jb++) {
        s16x4 pack;
        #pragma unroll
        for (int u = 0; u < 4; u++) {
            int j = jb * 4 + u;
            float a = 0.f;
            #pragma unroll
            for (int i = 0; i < DHEAD; i++) a += sc[i * DHEAD + j] * qr[i];
            pack[u] = (short)f2bbits(a);
        }
        *(s16x4*)(ovt + jb * 4) = pack;
    }
}

// ---------------- K8: final channel-LN, SINGLE read (values in registers) -
__global__ __launch_bounds__(256) void ln_final_kernel(
    const bf16* __restrict__ qkv, const float* __restrict__ g2, float* __restrict__ out)
{
    int tid = threadIdx.x;
    int p0 = blockIdx.x * 32, b = blockIdx.y;
    int pl = tid & 31, gq = tid >> 5;
    const bf16* xp = qkv + ((size_t)b * OQKV + CH) * NPOS + p0 + pl;
    float vals[64];
    float s = 0.f, s2 = 0.f;
    #pragma unroll
    for (int it = 0; it < 64; it++) {
        int c = it * 8 + gq;
        float v = b2f(xp[(size_t)c * NPOS]);
        vals[it] = v; s += v; s2 += v * v;
    }
    __shared__ float red[16][32];
    __shared__ float sm[32], sr[32];
    red[gq][pl] = s; red[8 + gq][pl] = s2;
    __syncthreads();
    if (tid < 32) {
        float ts = 0.f, ts2 = 0.f;
        #pragma unroll
        for (int u = 0; u < 8; u++) { ts += red[u][tid]; ts2 += red[8 + u][tid]; }
        float m   = ts * (1.f / CH);
        float var = ts2 * (1.f / CH) - m * m;
        sm[tid] = m;
        sr[tid] = rsqrtf(var + EPSF);
    }
    __syncthreads();
    float m = sm[pl], rs = sr[pl];
    float* op = out + (size_t)b * CH * NPOS + p0 + pl;
    #pragma unroll
    for (int it = 0; it < 64; it++) {
        int c = it * 8 + gq;
        op[(size_t)c * NPOS] = (vals[it] - m) * rs * g2[c];
    }
}

extern "C" void kernel_launch(void* const* d_in, const int* in_sizes, int n_in,
                              void* d_out, int out_size, void* d_ws, size_t ws_size,
                              hipStream_t stream)
{
    const float* x          = (const float*)d_in[0];
    const float* norm_g     = (const float*)d_in[1];
    const float* qkv_w      = (const float*)d_in[2];
    const float* out_w      = (const float*)d_in[3];
    const float* out_b      = (const float*)d_in[4];
    const float* out_norm_g = (const float*)d_in[5];
    float* outp = (float*)d_out;

    char* ws = (char*)d_ws;
    bf16*  qkv = (bf16*)ws;                                  // 201,326,592 B
    bf16*  wqb = (bf16*)(ws + (size_t)201326592);            // 1536*512 bf16
    bf16*  wob = wqb + (size_t)OQKV * CH;                    // 512*512 bf16
    float* ctx = (float*)(wob + (size_t)CH * CH);            // 4*16*8*64*64 f32
    bf16*  xnt = (bf16*)d_out;                               // xn^T scratch (first 64 MB of out)
    float2* kstat = (float2*)((char*)d_out + (size_t)67108864); // 64 KB scratch past xnt

    // 0. weight conversion
    cvt_kernel<<<dim3((OQKV * CH + 255) / 256), 256, 0, stream>>>(qkv_w, wqb, OQKV * CH);
    cvt_kernel<<<dim3((CH * CH + 255) / 256), 256, 0, stream>>>(out_w, wob, CH * CH);
    // 1. LN + transpose -> xn^T (single x read)
    ln_transpose_kernel<<<dim3(NPOS / 32, BATCH), 256, 0, stream>>>(x, norm_g, xnt);
    // 2. QKV projection: persistent MFMA, 256 blocks x 6 tiles
    mfma_gemm256p_kernel<6><<<dim3(256), 512, 0, stream>>>(
        wqb, xnt, (size_t)NPOS * CH, qkv, (size_t)OQKV * NPOS, nullptr);
    // 3. k softmax stats (no materialized normalize)
    k_stats_kernel<<<dim3(DHEAD, NHEAD, BATCH), 256, 0, stream>>>(qkv, kstat);
    // 4. context partials (k normalize fused)
    ctx_gemm_kernel<<<dim3(4, NHEAD, BATCH), 256, 0, stream>>>(qkv, kstat, ctx);
    // 5. attention out (incl. q softmax) -> v-slot transposed [n][hid]
    attn_out_kernel<<<dim3(16, NHEAD, BATCH), 256, 0, stream>>>(qkv, ctx);
    // 6. out projection + bias: persistent MFMA, 256 blocks x 2 tiles -> k-slot
    mfma_gemm256p_kernel<2><<<dim3(256), 512, 0, stream>>>(
        wob, qkv + (size_t)2 * CH * NPOS, (size_t)OQKV * NPOS,
        qkv + (size_t)CH * NPOS, (size_t)OQKV * NPOS, out_b);
    // 7. final LN -> d_out (overwrites scratch; scratch dead by now)
    ln_final_kernel<<<dim3(NPOS / 32, BATCH), 256, 0, stream>>>(qkv, out_norm_g, outp);
}

// Round 4
// 697.960 us; speedup vs baseline: 1.3955x; 1.2198x over previous
//
#include <hip/hip_runtime.h>
#include <hip/hip_bf16.h>
#include <cstddef>

typedef __hip_bfloat16 bf16;
typedef __attribute__((ext_vector_type(8))) short s16x8;
typedef __attribute__((ext_vector_type(4))) short s16x4;
typedef __attribute__((ext_vector_type(4))) float f32x4;

static constexpr int BATCH = 16;
static constexpr int CH    = 512;    // DIM
static constexpr int NPOS  = 4096;   // h*w
static constexpr int OQKV  = 1536;   // 3*HID
static constexpr int NHEAD = 8;
static constexpr int DHEAD = 64;
#define EPSF 1e-5f
#define QSCALE 0.125f

__device__ __forceinline__ float b2f(bf16 v){ return __bfloat162float(v); }
__device__ __forceinline__ bf16  f2b(float v){ return __float2bfloat16(v); }
__device__ __forceinline__ unsigned short f2bbits(float v){
    bf16 t = __float2bfloat16(v);
    return *reinterpret_cast<unsigned short*>(&t);
}
__device__ __forceinline__ float s2f(short s){
    union { unsigned u; float f; } c; c.u = ((unsigned)(unsigned short)s) << 16; return c.f;
}

// ---------------- K0: fp32 -> bf16 convert (weights) ----------------------
__global__ __launch_bounds__(256) void cvt_kernel(
    const float* __restrict__ in, bf16* __restrict__ out, int n)
{
    int i = blockIdx.x * 256 + threadIdx.x;
    if (i < n) out[i] = f2b(in[i]);
}

// ---------------- K1: fused chan-LN + transpose, SINGLE x read ------------
__global__ __launch_bounds__(256) void ln_transpose_kernel(
    const float* __restrict__ x, const float* __restrict__ g, bf16* __restrict__ xt)
{
    __shared__ unsigned short st[512][35];   // [c][p]
    __shared__ float red[16][32];
    __shared__ float sm[32], sr[32];
    __shared__ float gl[512];
    int tid = threadIdx.x;
    int p0 = blockIdx.x * 32, b = blockIdx.y;
    int pl = tid & 31, gq = tid >> 5;        // 8 channel-groups
    const float* xb = x + (size_t)b * CH * NPOS + p0;
    for (int i = tid; i < 512; i += 256) gl[i] = g[i];
    float s = 0.f, s2 = 0.f;
    #pragma unroll
    for (int it = 0; it < 64; it++) {
        int c = it * 8 + gq;
        float v = xb[(size_t)c * NPOS + pl];
        s += v; s2 += v * v;
        st[c][pl] = f2bbits(v);
    }
    red[gq][pl] = s; red[8 + gq][pl] = s2;
    __syncthreads();
    if (tid < 32) {
        float ts = 0.f, ts2 = 0.f;
        #pragma unroll
        for (int u = 0; u < 8; u++) { ts += red[u][tid]; ts2 += red[8 + u][tid]; }
        float m   = ts * (1.f / CH);
        float var = ts2 * (1.f / CH) - m * m;
        sm[tid] = m;
        sr[tid] = rsqrtf(var + EPSF);
    }
    __syncthreads();
    int r = tid >> 3, cl = tid & 7;
    float m = sm[r], rs = sr[r];
    bf16* orow = xt + ((size_t)b * NPOS + p0 + r) * CH;
    #pragma unroll
    for (int i2 = 0; i2 < 8; i2++) {
        s16x8 pk;
        #pragma unroll
        for (int u = 0; u < 8; u++) {
            int c = i2 * 64 + cl * 8 + u;
            float v = s2f((short)st[c][r]);
            pk[u] = (short)f2bbits((v - m) * rs * gl[c]);
        }
        *(s16x8*)(orow + i2 * 64 + cl * 8) = pk;
    }
}

// ---------------- K2/K7: persistent MFMA bf16 GEMM, 256x256 tiles ---------
template<int NOB>
__global__ __launch_bounds__(512, 2) void mfma_gemm256p_kernel(
    const bf16* __restrict__ A, const bf16* __restrict__ B, size_t Bbatch,
    bf16* __restrict__ C, size_t Cbatch, const float* __restrict__ bias)
{
    __shared__ alignas(16) short As[2][16384];
    __shared__ alignas(16) short Bs[2][16384];
    constexpr int NSTEPS = NOB * 8;
    int tid  = threadIdx.x;
    int lane = tid & 63, w = tid >> 6;
    int wr = w >> 2, wc = w & 3;
    int bid = blockIdx.x;

    f32x4 acc[8][4];
    #pragma unroll
    for (int i = 0; i < 8; i++)
        #pragma unroll
        for (int j = 0; j < 4; j++) acc[i][j] = f32x4{0.f, 0.f, 0.f, 0.f};

    auto decode = [&](int step, const bf16*& Ab, const bf16*& Bp,
                      int& oT, int& pT, int& b) {
        int L  = bid * NOB + (step >> 3);
        pT     = (L & 15) * 256;
        int rem = L >> 4;
        int oB  = rem % NOB;
        b       = rem / NOB;
        oT      = oB * 256;
        Ab = A + (size_t)oT * 512;
        Bp = B + (size_t)b * Bbatch + (size_t)pT * 512;
    };

    auto stageQ = [&](int d, const bf16* Ab, const bf16* Bp, int kT, int q) {
        int s = q * 512 + tid;
        int m = s & 255, c = s >> 8;
        const bf16* ga = Ab + (size_t)m * 512 + kT + c * 8;
        const bf16* gb = Bp + (size_t)m * 512 + kT + c * 8;
        int sbase = q * 512 + w * 64;
        __builtin_amdgcn_global_load_lds(
            (const __attribute__((address_space(1))) void*)ga,
            (__attribute__((address_space(3))) void*)(&As[d][(size_t)sbase * 8]), 16, 0, 0);
        __builtin_amdgcn_global_load_lds(
            (const __attribute__((address_space(1))) void*)gb,
            (__attribute__((address_space(3))) void*)(&Bs[d][(size_t)sbase * 8]), 16, 0, 0);
    };

    {
        const bf16 *A0, *B0; int o_, p_, b_;
        decode(0, A0, B0, o_, p_, b_);
        #pragma unroll
        for (int q = 0; q < 4; ++q) stageQ(0, A0, B0, 0, q);
    }

    #pragma unroll 1
    for (int s = 0; s < NSTEPS; ++s) {
        int cur = s & 1;
        bool hn = (s + 1) < NSTEPS;
        const bf16 *An = nullptr, *Bn = nullptr; int ktn = 0;
        if (hn) {
            int o_, p_, b_;
            decode(s + 1, An, Bn, o_, p_, b_);
            ktn = ((s + 1) & 7) * 64;
        }
        const s16x8* Av = (const s16x8*)As[cur];
        const s16x8* Bv = (const s16x8*)Bs[cur];
        s16x8 bfr[4];
        #pragma unroll
        for (int q = 0; q < 4; ++q) {
            const int kk = q >> 1, ih = q & 1;
            int cbase = kk * 4 + (lane >> 4);
            if (q == 0) {
                if (hn) {
                    stageQ(cur ^ 1, An, Bn, ktn, 0);
                    asm volatile("s_waitcnt vmcnt(2)" ::: "memory");
                } else {
                    asm volatile("s_waitcnt vmcnt(0)" ::: "memory");
                }
                __builtin_amdgcn_s_barrier();
                asm volatile("" ::: "memory");
            }
            s16x8 af[4];
            #pragma unroll
            for (int i = 0; i < 4; i++)
                af[i] = Av[cbase * 256 + wr * 128 + (ih * 4 + i) * 16 + (lane & 15)];
            if (ih == 0) {
                #pragma unroll
                for (int j = 0; j < 4; j++)
                    bfr[j] = Bv[cbase * 256 + wc * 64 + j * 16 + (lane & 15)];
            }
            if (q != 0) {
                if (hn) stageQ(cur ^ 1, An, Bn, ktn, q);
                __builtin_amdgcn_s_barrier();
            }
            asm volatile("s_waitcnt lgkmcnt(0)" ::: "memory");
            __builtin_amdgcn_sched_barrier(0);
            __builtin_amdgcn_s_setprio(1);
            #pragma unroll
            for (int i = 0; i < 4; i++)
                #pragma unroll
                for (int j = 0; j < 4; j++)
                    acc[ih * 4 + i][j] = __builtin_amdgcn_mfma_f32_16x16x32_bf16(
                        af[i], bfr[j], acc[ih * 4 + i][j], 0, 0, 0);
            __builtin_amdgcn_s_setprio(0);
            __builtin_amdgcn_sched_barrier(0);
            __builtin_amdgcn_s_barrier();
        }
        if ((s & 7) == 7) {
            const bf16 *d1, *d2; int oT, pT, b;
            decode(s, d1, d2, oT, pT, b);
            bf16* Cb = C + (size_t)b * Cbatch;
            #pragma unroll
            for (int i = 0; i < 8; i++) {
                #pragma unroll
                for (int r = 0; r < 4; r++) {
                    int o = oT + wr * 128 + i * 16 + (lane >> 4) * 4 + r;
                    float bv = bias ? bias[o] : 0.f;
                    #pragma unroll
                    for (int j = 0; j < 4; j++) {
                        int p = pT + wc * 64 + j * 16 + (lane & 15);
                        Cb[(size_t)o * NPOS + p] = f2b(acc[i][j][r] + bv);
                    }
                }
            }
            #pragma unroll
            for (int i = 0; i < 8; i++)
                #pragma unroll
                for (int j = 0; j < 4; j++) acc[i][j] = f32x4{0.f, 0.f, 0.f, 0.f};
        }
    }
}

// ---------------- K4: k softmax STATS only (max, 1/sum) over n ------------
__global__ __launch_bounds__(256) void k_stats_kernel(
    const bf16* __restrict__ qkv, float2* __restrict__ kstat)
{
    int d = blockIdx.x, m = blockIdx.y, b = blockIdx.z;
    const bf16* row = qkv + ((size_t)b * OQKV + CH + m * DHEAD + d) * NPOS;
    __shared__ float red[256];
    int tid = threadIdx.x;
    s16x8 v0 = *(const s16x8*)(row + tid * 16);
    s16x8 v1 = *(const s16x8*)(row + tid * 16 + 8);
    float r[16];
    #pragma unroll
    for (int u = 0; u < 8; u++) { r[u] = s2f(v0[u]); r[8 + u] = s2f(v1[u]); }
    float mx = -1e30f;
    #pragma unroll
    for (int u = 0; u < 16; u++) mx = fmaxf(mx, r[u]);
    red[tid] = mx; __syncthreads();
    for (int s = 128; s > 0; s >>= 1) { if (tid < s) red[tid] = fmaxf(red[tid], red[tid + s]); __syncthreads(); }
    mx = red[0]; __syncthreads();
    float sum = 0.f;
    #pragma unroll
    for (int u = 0; u < 16; u++) sum += expf(r[u] - mx);
    red[tid] = sum; __syncthreads();
    for (int s = 128; s > 0; s >>= 1) { if (tid < s) red[tid] += red[tid + s]; __syncthreads(); }
    if (tid == 0) {
        float2 st; st.x = mx; st.y = 1.f / red[0];
        kstat[((size_t)b * NHEAD + m) * DHEAD + d] = st;
    }
}

// ---------------- K5: context partials via MFMA ---------------------------
// ctx[i][j] = sum_n exp(k[i,n]-mx_i)*inv_i * v[j,n]  per (b,m,nsplit).
// 4 waves, wave w owns i-band w*16. A-frag: k~ bf16 built in-register;
// B-frag: raw v bits. Both loaded straight from global as s16x8
// (16 rows x 64 B per instruction -> fully coalesced, L2-resident).
__global__ __launch_bounds__(256) void ctx_mfma_kernel(
    const bf16* __restrict__ qkv, const float2* __restrict__ kstat,
    float* __restrict__ ctx)
{
    int tid = threadIdx.x;
    int lane = tid & 63, w = tid >> 6;
    int lr = lane & 15, lc = lane >> 4;
    int split = blockIdx.x, m = blockIdx.y, b = blockIdx.z;
    int nBase = split * (NPOS / 4);
    int iBand = w * 16;
    const bf16* kb = qkv + ((size_t)b * OQKV + CH     + m * DHEAD) * NPOS;
    const bf16* vb = qkv + ((size_t)b * OQKV + 2 * CH + m * DHEAD) * NPOS;
    float2 st = kstat[((size_t)b * NHEAD + m) * DHEAD + iBand + lr];
    const float mx = st.x, inv = st.y;
    const bf16* ka  = kb + (size_t)(iBand + lr) * NPOS + nBase + lc * 8;
    const bf16* va0 = vb + (size_t)(lr)      * NPOS + nBase + lc * 8;
    const bf16* va1 = va0 + (size_t)16 * NPOS;
    const bf16* va2 = va0 + (size_t)32 * NPOS;
    const bf16* va3 = va0 + (size_t)48 * NPOS;
    f32x4 acc0 = {0.f,0.f,0.f,0.f}, acc1 = {0.f,0.f,0.f,0.f};
    f32x4 acc2 = {0.f,0.f,0.f,0.f}, acc3 = {0.f,0.f,0.f,0.f};
    #pragma unroll 4
    for (int ch = 0; ch < 32; ++ch) {
        int off = ch * 32;
        s16x8 kraw = *(const s16x8*)(ka  + off);
        s16x8 b0   = *(const s16x8*)(va0 + off);
        s16x8 b1   = *(const s16x8*)(va1 + off);
        s16x8 b2   = *(const s16x8*)(va2 + off);
        s16x8 b3   = *(const s16x8*)(va3 + off);
        s16x8 af;
        #pragma unroll
        for (int u = 0; u < 8; u++)
            af[u] = (short)f2bbits(expf(s2f(kraw[u]) - mx) * inv);
        acc0 = __builtin_amdgcn_mfma_f32_16x16x32_bf16(af, b0, acc0, 0, 0, 0);
        acc1 = __builtin_amdgcn_mfma_f32_16x16x32_bf16(af, b1, acc1, 0, 0, 0);
        acc2 = __builtin_amdgcn_mfma_f32_16x16x32_bf16(af, b2, acc2, 0, 0, 0);
        acc3 = __builtin_amdgcn_mfma_f32_16x16x32_bf16(af, b3, acc3, 0, 0, 0);
    }
    float* cb = ctx + ((size_t)split * BATCH * NHEAD + b * NHEAD + m) * (DHEAD * DHEAD);
    #pragma unroll
    for (int r = 0; r < 4; r++) {
        int i = iBand + lc * 4 + r;        // D: row=(lane>>4)*4+r, col=lane&15
        cb[i * 64 +  0 + lr] = acc0[r];
        cb[i * 64 + 16 + lr] = acc1[r];
        cb[i * 64 + 32 + lr] = acc2[r];
        cb[i * 64 + 48 + lr] = acc3[r];
    }
}

// ---------------- K6: fused q-softmax + O^T[n][j] = sum_i q~[i,n] ctxS[i,j]
// via MFMA -> v-slot TRANSPOSED [n][hid].
// Phase 1: per-thread q softmax (regs) -> q~^T in XOR-swizzled LDS [n][i];
//          ctx partials summed -> bf16 XOR-swizzled LDS [j][i].
// Phase 2: per wave: hoist 8 ctx B-frags to regs; per 16-n subtile:
//          2 ds_read A-frags + 8 MFMA; scalar bf16 stores.
__global__ __launch_bounds__(256) void attn_out_kernel(
    bf16* __restrict__ qkv, const float* __restrict__ ctx)
{
    __shared__ unsigned short qt[256 * 64];   // swizzled [n][i], 32 KB
    __shared__ unsigned short cst[64 * 64];   // swizzled [j][i], 8 KB
    int tid = threadIdx.x;
    int nT = blockIdx.x * 256;
    int m = blockIdx.y, b = blockIdx.z;
    size_t cbase = (size_t)(b * NHEAD + m) * (DHEAD * DHEAD);
    constexpr size_t CSPLIT = (size_t)BATCH * NHEAD * DHEAD * DHEAD;
    {
        int i = tid >> 2, j0 = (tid & 3) * 16;   // fixed i, 16 consecutive j
        #pragma unroll
        for (int e = 0; e < 16; e++) {
            int j = j0 + e;
            size_t l = cbase + (size_t)i * 64 + j;
            float v = ctx[l] + ctx[CSPLIT + l] + ctx[2 * CSPLIT + l] + ctx[3 * CSPLIT + l];
            cst[j * 64 + (((i >> 3) ^ (j & 7)) * 8) + (i & 7)] = f2bbits(v);
        }
    }
    // q softmax for n = nT + tid (raw q -> q~ incl. QSCALE)
    const bf16* q = qkv + ((size_t)b * OQKV + m * DHEAD) * NPOS + nT + tid;
    float qr[DHEAD];
    float mx = -1e30f;
    #pragma unroll
    for (int i = 0; i < DHEAD; i++) { qr[i] = b2f(q[(size_t)i * NPOS]); mx = fmaxf(mx, qr[i]); }
    float s = 0.f;
    #pragma unroll
    for (int i = 0; i < DHEAD; i++) { qr[i] = expf(qr[i] - mx); s += qr[i]; }
    float inv = QSCALE / s;
    #pragma unroll
    for (int s8 = 0; s8 < 8; s8++) {
        s16x8 pk;
        #pragma unroll
        for (int u = 0; u < 8; u++) pk[u] = (short)f2bbits(qr[s8 * 8 + u] * inv);
        *(s16x8*)&qt[tid * 64 + ((s8 ^ (tid & 7)) * 8)] = pk;
    }
    __syncthreads();
    int lane = tid & 63, w = tid >> 6, lr = lane & 15, lc = lane >> 4;
    // hoist B-frags: B[row=j][k=i] = cst[j][i], j = jb*16+lr, i-chunk kc*32+lc*8
    s16x8 bf2[4][2];
    #pragma unroll
    for (int jb = 0; jb < 4; jb++)
        #pragma unroll
        for (int kc = 0; kc < 2; kc++)
            bf2[jb][kc] = *(const s16x8*)&cst[(jb * 16 + lr) * 64 + (((kc * 4 + lc) ^ (lr & 7)) * 8)];
    bf16* ovt = qkv + ((size_t)b * OQKV + 2 * CH) * NPOS;
    #pragma unroll
    for (int sub = 0; sub < 4; ++sub) {
        int nl = w * 64 + sub * 16 + lr;      // A row (local n)
        s16x8 a0 = *(const s16x8*)&qt[nl * 64 + (((0 + lc) ^ (nl & 7)) * 8)];
        s16x8 a1 = *(const s16x8*)&qt[nl * 64 + (((4 + lc) ^ (nl & 7)) * 8)];
        #pragma unroll
        for (int jb = 0; jb < 4; jb++) {
            f32x4 acc = f32x4{0.f, 0.f, 0.f, 0.f};
            acc = __builtin_amdgcn_mfma_f32_16x16x32_bf16(a0, bf2[jb][0], acc, 0, 0, 0);
            acc = __builtin_amdgcn_mfma_f32_16x16x32_bf16(a1, bf2[jb][1], acc, 0, 0, 0);
            #pragma unroll
            for (int r = 0; r < 4; r++) {
                int nrow = nT + w * 64 + sub * 16 + lc * 4 + r;   // D row
                ovt[(size_t)nrow * CH + m * DHEAD + jb * 16 + lr] = f2b(acc[r]);
            }
        }
    }
}

// ---------------- K8: final channel-LN, SINGLE read (values in registers) -
__global__ __launch_bounds__(256) void ln_final_kernel(
    const bf16* __restrict__ qkv, const float* __restrict__ g2, float* __restrict__ out)
{
    int tid = threadIdx.x;
    int p0 = blockIdx.x * 32, b = blockIdx.y;
    int pl = tid & 31, gq = tid >> 5;
    const bf16* xp = qkv + ((size_t)b * OQKV + CH) * NPOS + p0 + pl;
    float vals[64];
    float s = 0.f, s2 = 0.f;
    #pragma unroll
    for (int it = 0; it < 64; it++) {
        int c = it * 8 + gq;
        float v = b2f(xp[(size_t)c * NPOS]);
        vals[it] = v; s += v; s2 += v * v;
    }
    __shared__ float red[16][32];
    __shared__ float sm[32], sr[32];
    red[gq][pl] = s; red[8 + gq][pl] = s2;
    __syncthreads();
    if (tid < 32) {
        float ts = 0.f, ts2 = 0.f;
        #pragma unroll
        for (int u = 0; u < 8; u++) { ts += red[u][tid]; ts2 += red[8 + u][tid]; }
        float m   = ts * (1.f / CH);
        float var = ts2 * (1.f / CH) - m * m;
        sm[tid] = m;
        sr[tid] = rsqrtf(var + EPSF);
    }
    __syncthreads();
    float m = sm[pl], rs = sr[pl];
    float* op = out + (size_t)b * CH * NPOS + p0 + pl;
    #pragma unroll
    for (int it = 0; it < 64; it++) {
        int c = it * 8 + gq;
        op[(size_t)c * NPOS] = (vals[it] - m) * rs * g2[c];
    }
}

extern "C" void kernel_launch(void* const* d_in, const int* in_sizes, int n_in,
                              void* d_out, int out_size, void* d_ws, size_t ws_size,
                              hipStream_t stream)
{
    const float* x          = (const float*)d_in[0];
    const float* norm_g     = (const float*)d_in[1];
    const float* qkv_w      = (const float*)d_in[2];
    const float* out_w      = (const float*)d_in[3];
    const float* out_b      = (const float*)d_in[4];
    const float* out_norm_g = (const float*)d_in[5];
    float* outp = (float*)d_out;

    char* ws = (char*)d_ws;
    bf16*  qkv = (bf16*)ws;                                  // 201,326,592 B
    bf16*  wqb = (bf16*)(ws + (size_t)201326592);            // 1536*512 bf16
    bf16*  wob = wqb + (size_t)OQKV * CH;                    // 512*512 bf16
    float* ctx = (float*)(wob + (size_t)CH * CH);            // 4*16*8*64*64 f32
    bf16*  xnt = (bf16*)d_out;                               // xn^T scratch (first 64 MB of out)
    float2* kstat = (float2*)((char*)d_out + (size_t)67108864); // 64 KB scratch past xnt

    // 0. weight conversion
    cvt_kernel<<<dim3((OQKV * CH + 255) / 256), 256, 0, stream>>>(qkv_w, wqb, OQKV * CH);
    cvt_kernel<<<dim3((CH * CH + 255) / 256), 256, 0, stream>>>(out_w, wob, CH * CH);
    // 1. LN + transpose -> xn^T (single x read)
    ln_transpose_kernel<<<dim3(NPOS / 32, BATCH), 256, 0, stream>>>(x, norm_g, xnt);
    // 2. QKV projection: persistent MFMA, 256 blocks x 6 tiles
    mfma_gemm256p_kernel<6><<<dim3(256), 512, 0, stream>>>(
        wqb, xnt, (size_t)NPOS * CH, qkv, (size_t)OQKV * NPOS, nullptr);
    // 3. k softmax stats (no materialized normalize)
    k_stats_kernel<<<dim3(DHEAD, NHEAD, BATCH), 256, 0, stream>>>(qkv, kstat);
    // 4. context partials via MFMA (k normalize fused)
    ctx_mfma_kernel<<<dim3(4, NHEAD, BATCH), 256, 0, stream>>>(qkv, kstat, ctx);
    // 5. attention out via MFMA (incl. q softmax) -> v-slot transposed [n][hid]
    attn_out_kernel<<<dim3(16, NHEAD, BATCH), 256, 0, stream>>>(qkv, ctx);
    // 6. out projection + bias: persistent MFMA, 256 blocks x 2 tiles -> k-slot
    mfma_gemm256p_kernel<2><<<dim3(256), 512, 0, stream>>>(
        wob, qkv + (size_t)2 * CH * NPOS, (size_t)OQKV * NPOS,
        qkv + (size_t)CH * NPOS, (size_t)OQKV * NPOS, out_b);
    // 7. final LN -> d_out (overwrites scratch; scratch dead by now)
    ln_final_kernel<<<dim3(NPOS / 32, BATCH), 256, 0, stream>>>(qkv, out_norm_g, outp);
}

// Round 5
// 574.553 us; speedup vs baseline: 1.6952x; 1.2148x over previous
//
#include <hip/hip_runtime.h>
#include <hip/hip_bf16.h>
#include <cstddef>

typedef __hip_bfloat16 bf16;
typedef __attribute__((ext_vector_type(8))) short s16x8;
typedef __attribute__((ext_vector_type(4))) short s16x4;
typedef __attribute__((ext_vector_type(4))) float f32x4;

static constexpr int BATCH = 16;
static constexpr int CH    = 512;    // DIM
static constexpr int NPOS  = 4096;   // h*w
static constexpr int OQKV  = 1536;   // 3*HID
static constexpr int NHEAD = 8;
static constexpr int DHEAD = 64;
#define EPSF 1e-5f
#define QSCALE 0.125f

__device__ __forceinline__ float b2f(bf16 v){ return __bfloat162float(v); }
__device__ __forceinline__ bf16  f2b(float v){ return __float2bfloat16(v); }
__device__ __forceinline__ unsigned short f2bbits(float v){
    bf16 t = __float2bfloat16(v);
    return *reinterpret_cast<unsigned short*>(&t);
}
__device__ __forceinline__ float s2f(short s){
    union { unsigned u; float f; } c; c.u = ((unsigned)(unsigned short)s) << 16; return c.f;
}
// slot index (16B units) of operand[row][kchunk cb] in the XOR-micro-tiled
// LDS layout: [rowgroup=row>>3][rowlow=row&7][kcfield = cb ^ (row&7)]
__device__ __forceinline__ int swzslot(int row, int cb) {
    return ((row >> 3) << 6) + ((row & 7) << 3) + (cb ^ (row & 7));
}

// ---------------- K0: fp32 -> bf16 convert (weights) ----------------------
__global__ __launch_bounds__(256) void cvt_kernel(
    const float* __restrict__ in, bf16* __restrict__ out, int n)
{
    int i = blockIdx.x * 256 + threadIdx.x;
    if (i < n) out[i] = f2b(in[i]);
}

// ---------------- K1: fused chan-LN + transpose, SINGLE x read ------------
__global__ __launch_bounds__(256) void ln_transpose_kernel(
    const float* __restrict__ x, const float* __restrict__ g, bf16* __restrict__ xt)
{
    __shared__ unsigned short st[512][35];   // [c][p]
    __shared__ float red[16][32];
    __shared__ float sm[32], sr[32];
    __shared__ float gl[512];
    int tid = threadIdx.x;
    int p0 = blockIdx.x * 32, b = blockIdx.y;
    int pl = tid & 31, gq = tid >> 5;        // 8 channel-groups
    const float* xb = x + (size_t)b * CH * NPOS + p0;
    for (int i = tid; i < 512; i += 256) gl[i] = g[i];
    float s = 0.f, s2 = 0.f;
    #pragma unroll
    for (int it = 0; it < 64; it++) {
        int c = it * 8 + gq;
        float v = xb[(size_t)c * NPOS + pl];
        s += v; s2 += v * v;
        st[c][pl] = f2bbits(v);
    }
    red[gq][pl] = s; red[8 + gq][pl] = s2;
    __syncthreads();
    if (tid < 32) {
        float ts = 0.f, ts2 = 0.f;
        #pragma unroll
        for (int u = 0; u < 8; u++) { ts += red[u][tid]; ts2 += red[8 + u][tid]; }
        float m   = ts * (1.f / CH);
        float var = ts2 * (1.f / CH) - m * m;
        sm[tid] = m;
        sr[tid] = rsqrtf(var + EPSF);
    }
    __syncthreads();
    int r = tid >> 3, cl = tid & 7;
    float m = sm[r], rs = sr[r];
    bf16* orow = xt + ((size_t)b * NPOS + p0 + r) * CH;
    #pragma unroll
    for (int i2 = 0; i2 < 8; i2++) {
        s16x8 pk;
        #pragma unroll
        for (int u = 0; u < 8; u++) {
            int c = i2 * 64 + cl * 8 + u;
            float v = s2f((short)st[c][r]);
            pk[u] = (short)f2bbits((v - m) * rs * gl[c]);
        }
        *(s16x8*)(orow + i2 * 64 + cl * 8) = pk;
    }
}

// ---------------- K2/K7: persistent MFMA bf16 GEMM, 256x256 tiles ---------
// Staging now COALESCED: one wave-inst covers 8 rows x 128 B contiguous
// (XOR-permuted kchunks within each row segment -> same cache lines).
// LDS linear dest (gload_lds requirement); fragment ds_read uses the same
// XOR -> uniform bank load (8 lanes/quad, balanced).
template<int NOB>
__global__ __launch_bounds__(512, 2) void mfma_gemm256p_kernel(
    const bf16* __restrict__ A, const bf16* __restrict__ B, size_t Bbatch,
    bf16* __restrict__ C, size_t Cbatch, const float* __restrict__ bias)
{
    __shared__ alignas(16) short As[2][16384];
    __shared__ alignas(16) short Bs[2][16384];
    constexpr int NSTEPS = NOB * 8;
    int tid  = threadIdx.x;
    int lane = tid & 63, w = tid >> 6;
    int wr = w >> 2, wc = w & 3;
    int bid = blockIdx.x;

    f32x4 acc[8][4];
    #pragma unroll
    for (int i = 0; i < 8; i++)
        #pragma unroll
        for (int j = 0; j < 4; j++) acc[i][j] = f32x4{0.f, 0.f, 0.f, 0.f};

    auto decode = [&](int step, const bf16*& Ab, const bf16*& Bp,
                      int& oT, int& pT, int& b) {
        int L  = bid * NOB + (step >> 3);
        pT     = (L & 15) * 256;
        int rem = L >> 4;
        int oB  = rem % NOB;
        b       = rem / NOB;
        oT      = oB * 256;
        Ab = A + (size_t)oT * 512;
        Bp = B + (size_t)b * Bbatch + (size_t)pT * 512;
    };

    // stage quarter q of step's 256x64 K-tile (A and B) into buffer d.
    // slot s = q*512+tid: rg=s>>6, rl=(s>>3)&7, kcf=s&7; content =
    // operand[rg*8+rl][kcf ^ rl]  (XOR involution, rule #21 both-sides).
    auto stageQ = [&](int d, const bf16* Ab, const bf16* Bp, int kT, int q) {
        int s   = q * 512 + tid;
        int rl  = (s >> 3) & 7;
        int row = ((s >> 6) << 3) + rl;
        int kcs = (s & 7) ^ rl;              // pre-swizzled source kchunk
        const bf16* ga = Ab + (size_t)row * 512 + kT + kcs * 8;
        const bf16* gb = Bp + (size_t)row * 512 + kT + kcs * 8;
        int sbase = q * 512 + w * 64;        // wave-uniform; lane l -> slot sbase+l
        __builtin_amdgcn_global_load_lds(
            (const __attribute__((address_space(1))) void*)ga,
            (__attribute__((address_space(3))) void*)(&As[d][(size_t)sbase * 8]), 16, 0, 0);
        __builtin_amdgcn_global_load_lds(
            (const __attribute__((address_space(1))) void*)gb,
            (__attribute__((address_space(3))) void*)(&Bs[d][(size_t)sbase * 8]), 16, 0, 0);
    };

    {
        const bf16 *A0, *B0; int o_, p_, b_;
        decode(0, A0, B0, o_, p_, b_);
        #pragma unroll
        for (int q = 0; q < 4; ++q) stageQ(0, A0, B0, 0, q);
    }

    #pragma unroll 1
    for (int s = 0; s < NSTEPS; ++s) {
        int cur = s & 1;
        bool hn = (s + 1) < NSTEPS;
        const bf16 *An = nullptr, *Bn = nullptr; int ktn = 0;
        if (hn) {
            int o_, p_, b_;
            decode(s + 1, An, Bn, o_, p_, b_);
            ktn = ((s + 1) & 7) * 64;
        }
        const s16x8* Av = (const s16x8*)As[cur];
        const s16x8* Bv = (const s16x8*)Bs[cur];
        s16x8 bfr[4];
        #pragma unroll
        for (int q = 0; q < 4; ++q) {
            const int ih = q & 1;
            int cbase = (q >> 1) * 4 + (lane >> 4);
            if (q == 0) {
                if (hn) {
                    stageQ(cur ^ 1, An, Bn, ktn, 0);
                    asm volatile("s_waitcnt vmcnt(2)" ::: "memory");
                } else {
                    asm volatile("s_waitcnt vmcnt(0)" ::: "memory");
                }
                __builtin_amdgcn_s_barrier();
                asm volatile("" ::: "memory");
            }
            s16x8 af[4];
            #pragma unroll
            for (int i = 0; i < 4; i++)
                af[i] = Av[swzslot(wr * 128 + (ih * 4 + i) * 16 + (lane & 15), cbase)];
            if (ih == 0) {
                #pragma unroll
                for (int j = 0; j < 4; j++)
                    bfr[j] = Bv[swzslot(wc * 64 + j * 16 + (lane & 15), cbase)];
            }
            if (q != 0) {
                if (hn) stageQ(cur ^ 1, An, Bn, ktn, q);
                __builtin_amdgcn_s_barrier();
            }
            asm volatile("s_waitcnt lgkmcnt(0)" ::: "memory");
            __builtin_amdgcn_sched_barrier(0);
            __builtin_amdgcn_s_setprio(1);
            #pragma unroll
            for (int i = 0; i < 4; i++)
                #pragma unroll
                for (int j = 0; j < 4; j++)
                    acc[ih * 4 + i][j] = __builtin_amdgcn_mfma_f32_16x16x32_bf16(
                        af[i], bfr[j], acc[ih * 4 + i][j], 0, 0, 0);
            __builtin_amdgcn_s_setprio(0);
            __builtin_amdgcn_sched_barrier(0);
            __builtin_amdgcn_s_barrier();
        }
        if ((s & 7) == 7) {
            const bf16 *d1, *d2; int oT, pT, b;
            decode(s, d1, d2, oT, pT, b);
            bf16* Cb = C + (size_t)b * Cbatch;
            #pragma unroll
            for (int i = 0; i < 8; i++) {
                #pragma unroll
                for (int r = 0; r < 4; r++) {
                    int o = oT + wr * 128 + i * 16 + (lane >> 4) * 4 + r;
                    float bv = bias ? bias[o] : 0.f;
                    #pragma unroll
                    for (int j = 0; j < 4; j++) {
                        int p = pT + wc * 64 + j * 16 + (lane & 15);
                        Cb[(size_t)o * NPOS + p] = f2b(acc[i][j][r] + bv);
                    }
                }
            }
            #pragma unroll
            for (int i = 0; i < 8; i++)
                #pragma unroll
                for (int j = 0; j < 4; j++) acc[i][j] = f32x4{0.f, 0.f, 0.f, 0.f};
        }
    }
}

// ---------------- K4: k softmax STATS only (max, 1/sum) over n ------------
__global__ __launch_bounds__(256) void k_stats_kernel(
    const bf16* __restrict__ qkv, float2* __restrict__ kstat)
{
    int d = blockIdx.x, m = blockIdx.y, b = blockIdx.z;
    const bf16* row = qkv + ((size_t)b * OQKV + CH + m * DHEAD + d) * NPOS;
    __shared__ float red[256];
    int tid = threadIdx.x;
    s16x8 v0 = *(const s16x8*)(row + tid * 16);
    s16x8 v1 = *(const s16x8*)(row + tid * 16 + 8);
    float r[16];
    #pragma unroll
    for (int u = 0; u < 8; u++) { r[u] = s2f(v0[u]); r[8 + u] = s2f(v1[u]); }
    float mx = -1e30f;
    #pragma unroll
    for (int u = 0; u < 16; u++) mx = fmaxf(mx, r[u]);
    red[tid] = mx; __syncthreads();
    for (int s = 128; s > 0; s >>= 1) { if (tid < s) red[tid] = fmaxf(red[tid], red[tid + s]); __syncthreads(); }
    mx = red[0]; __syncthreads();
    float sum = 0.f;
    #pragma unroll
    for (int u = 0; u < 16; u++) sum += __expf(r[u] - mx);
    red[tid] = sum; __syncthreads();
    for (int s = 128; s > 0; s >>= 1) { if (tid < s) red[tid] += red[tid + s]; __syncthreads(); }
    if (tid == 0) {
        float2 st; st.x = mx; st.y = 1.f / red[0];
        kstat[((size_t)b * NHEAD + m) * DHEAD + d] = st;
    }
}

// ---------------- K5: context partials via MFMA ---------------------------
__global__ __launch_bounds__(256) void ctx_mfma_kernel(
    const bf16* __restrict__ qkv, const float2* __restrict__ kstat,
    float* __restrict__ ctx)
{
    int tid = threadIdx.x;
    int lane = tid & 63, w = tid >> 6;
    int lr = lane & 15, lc = lane >> 4;
    int split = blockIdx.x, m = blockIdx.y, b = blockIdx.z;
    int nBase = split * (NPOS / 4);
    int iBand = w * 16;
    const bf16* kb = qkv + ((size_t)b * OQKV + CH     + m * DHEAD) * NPOS;
    const bf16* vb = qkv + ((size_t)b * OQKV + 2 * CH + m * DHEAD) * NPOS;
    float2 st = kstat[((size_t)b * NHEAD + m) * DHEAD + iBand + lr];
    const float mx = st.x, inv = st.y;
    const bf16* ka  = kb + (size_t)(iBand + lr) * NPOS + nBase + lc * 8;
    const bf16* va0 = vb + (size_t)(lr)      * NPOS + nBase + lc * 8;
    const bf16* va1 = va0 + (size_t)16 * NPOS;
    const bf16* va2 = va0 + (size_t)32 * NPOS;
    const bf16* va3 = va0 + (size_t)48 * NPOS;
    f32x4 acc0 = {0.f,0.f,0.f,0.f}, acc1 = {0.f,0.f,0.f,0.f};
    f32x4 acc2 = {0.f,0.f,0.f,0.f}, acc3 = {0.f,0.f,0.f,0.f};
    #pragma unroll 4
    for (int ch = 0; ch < 32; ++ch) {
        int off = ch * 32;
        s16x8 kraw = *(const s16x8*)(ka  + off);
        s16x8 b0   = *(const s16x8*)(va0 + off);
        s16x8 b1   = *(const s16x8*)(va1 + off);
        s16x8 b2   = *(const s16x8*)(va2 + off);
        s16x8 b3   = *(const s16x8*)(va3 + off);
        s16x8 af;
        #pragma unroll
        for (int u = 0; u < 8; u++)
            af[u] = (short)f2bbits(__expf(s2f(kraw[u]) - mx) * inv);
        acc0 = __builtin_amdgcn_mfma_f32_16x16x32_bf16(af, b0, acc0, 0, 0, 0);
        acc1 = __builtin_amdgcn_mfma_f32_16x16x32_bf16(af, b1, acc1, 0, 0, 0);
        acc2 = __builtin_amdgcn_mfma_f32_16x16x32_bf16(af, b2, acc2, 0, 0, 0);
        acc3 = __builtin_amdgcn_mfma_f32_16x16x32_bf16(af, b3, acc3, 0, 0, 0);
    }
    float* cb = ctx + ((size_t)split * BATCH * NHEAD + b * NHEAD + m) * (DHEAD * DHEAD);
    #pragma unroll
    for (int r = 0; r < 4; r++) {
        int i = iBand + lc * 4 + r;        // D: row=(lane>>4)*4+r, col=lane&15
        cb[i * 64 +  0 + lr] = acc0[r];
        cb[i * 64 + 16 + lr] = acc1[r];
        cb[i * 64 + 32 + lr] = acc2[r];
        cb[i * 64 + 48 + lr] = acc3[r];
    }
}

// ---------------- K6: fused q-softmax + O^T via MFMA -> v-slot [n][hid] ---
__global__ __launch_bounds__(256) void attn_out_kernel(
    bf16* __restrict__ qkv, const float* __restrict__ ctx)
{
    __shared__ unsigned short qt[256 * 64];   // swizzled [n][i], 32 KB
    __shared__ unsigned short cst[64 * 64];   // swizzled [j][i], 8 KB
    int tid = threadIdx.x;
    int nT = blockIdx.x * 256;
    int m = blockIdx.y, b = blockIdx.z;
    size_t cbase = (size_t)(b * NHEAD + m) * (DHEAD * DHEAD);
    constexpr size_t CSPLIT = (size_t)BATCH * NHEAD * DHEAD * DHEAD;
    {
        int i = tid >> 2, j0 = (tid & 3) * 16;   // fixed i, 16 consecutive j
        #pragma unroll
        for (int e = 0; e < 16; e++) {
            int j = j0 + e;
            size_t l = cbase + (size_t)i * 64 + j;
            float v = ctx[l] + ctx[CSPLIT + l] + ctx[2 * CSPLIT + l] + ctx[3 * CSPLIT + l];
            cst[j * 64 + (((i >> 3) ^ (j & 7)) * 8) + (i & 7)] = f2bbits(v);
        }
    }
    const bf16* q = qkv + ((size_t)b * OQKV + m * DHEAD) * NPOS + nT + tid;
    float qr[DHEAD];
    float mx = -1e30f;
    #pragma unroll
    for (int i = 0; i < DHEAD; i++) { qr[i] = b2f(q[(size_t)i * NPOS]); mx = fmaxf(mx, qr[i]); }
    float s = 0.f;
    #pragma unroll
    for (int i = 0; i < DHEAD; i++) { qr[i] = __expf(qr[i] - mx); s += qr[i]; }
    float inv = QSCALE / s;
    #pragma unroll
    for (int s8 = 0; s8 < 8; s8++) {
        s16x8 pk;
        #pragma unroll
        for (int u = 0; u < 8; u++) pk[u] = (short)f2bbits(qr[s8 * 8 + u] * inv);
        *(s16x8*)&qt[tid * 64 + ((s8 ^ (tid & 7)) * 8)] = pk;
    }
    __syncthreads();
    int lane = tid & 63, w = tid >> 6, lr = lane & 15, lc = lane >> 4;
    s16x8 bf2[4][2];
    #pragma unroll
    for (int jb = 0; jb < 4; jb++)
        #pragma unroll
        for (int kc = 0; kc < 2; kc++)
            bf2[jb][kc] = *(const s16x8*)&cst[(jb * 16 + lr) * 64 + (((kc * 4 + lc) ^ (lr & 7)) * 8)];
    bf16* ovt = qkv + ((size_t)b * OQKV + 2 * CH) * NPOS;
    #pragma unroll
    for (int sub = 0; sub < 4; ++sub) {
        int nl = w * 64 + sub * 16 + lr;      // A row (local n)
        s16x8 a0 = *(const s16x8*)&qt[nl * 64 + (((0 + lc) ^ (nl & 7)) * 8)];
        s16x8 a1 = *(const s16x8*)&qt[nl * 64 + (((4 + lc) ^ (nl & 7)) * 8)];
        #pragma unroll
        for (int jb = 0; jb < 4; jb++) {
            f32x4 acc = f32x4{0.f, 0.f, 0.f, 0.f};
            acc = __builtin_amdgcn_mfma_f32_16x16x32_bf16(a0, bf2[jb][0], acc, 0, 0, 0);
            acc = __builtin_amdgcn_mfma_f32_16x16x32_bf16(a1, bf2[jb][1], acc, 0, 0, 0);
            #pragma unroll
            for (int r = 0; r < 4; r++) {
                int nrow = nT + w * 64 + sub * 16 + lc * 4 + r;   // D row
                ovt[(size_t)nrow * CH + m * DHEAD + jb * 16 + lr] = f2b(acc[r]);
            }
        }
    }
}

// ---------------- K8: final channel-LN, SINGLE read (values in registers) -
__global__ __launch_bounds__(256) void ln_final_kernel(
    const bf16* __restrict__ qkv, const float* __restrict__ g2, float* __restrict__ out)
{
    int tid = threadIdx.x;
    int p0 = blockIdx.x * 32, b = blockIdx.y;
    int pl = tid & 31, gq = tid >> 5;
    const bf16* xp = qkv + ((size_t)b * OQKV + CH) * NPOS + p0 + pl;
    float vals[64];
    float s = 0.f, s2 = 0.f;
    #pragma unroll
    for (int it = 0; it < 64; it++) {
        int c = it * 8 + gq;
        float v = b2f(xp[(size_t)c * NPOS]);
        vals[it] = v; s += v; s2 += v * v;
    }
    __shared__ float red[16][32];
    __shared__ float sm[32], sr[32];
    red[gq][pl] = s; red[8 + gq][pl] = s2;
    __syncthreads();
    if (tid < 32) {
        float ts = 0.f, ts2 = 0.f;
        #pragma unroll
        for (int u = 0; u < 8; u++) { ts += red[u][tid]; ts2 += red[8 + u][tid]; }
        float m   = ts * (1.f / CH);
        float var = ts2 * (1.f / CH) - m * m;
        sm[tid] = m;
        sr[tid] = rsqrtf(var + EPSF);
    }
    __syncthreads();
    float m = sm[pl], rs = sr[pl];
    float* op = out + (size_t)b * CH * NPOS + p0 + pl;
    #pragma unroll
    for (int it = 0; it < 64; it++) {
        int c = it * 8 + gq;
        op[(size_t)c * NPOS] = (vals[it] - m) * rs * g2[c];
    }
}

extern "C" void kernel_launch(void* const* d_in, const int* in_sizes, int n_in,
                              void* d_out, int out_size, void* d_ws, size_t ws_size,
                              hipStream_t stream)
{
    const float* x          = (const float*)d_in[0];
    const float* norm_g     = (const float*)d_in[1];
    const float* qkv_w      = (const float*)d_in[2];
    const float* out_w      = (const float*)d_in[3];
    const float* out_b      = (const float*)d_in[4];
    const float* out_norm_g = (const float*)d_in[5];
    float* outp = (float*)d_out;

    char* ws = (char*)d_ws;
    bf16*  qkv = (bf16*)ws;                                  // 201,326,592 B
    bf16*  wqb = (bf16*)(ws + (size_t)201326592);            // 1536*512 bf16
    bf16*  wob = wqb + (size_t)OQKV * CH;                    // 512*512 bf16
    float* ctx = (float*)(wob + (size_t)CH * CH);            // 4*16*8*64*64 f32
    bf16*  xnt = (bf16*)d_out;                               // xn^T scratch (first 64 MB of out)
    float2* kstat = (float2*)((char*)d_out + (size_t)67108864); // 64 KB scratch past xnt

    // 0. weight conversion
    cvt_kernel<<<dim3((OQKV * CH + 255) / 256), 256, 0, stream>>>(qkv_w, wqb, OQKV * CH);
    cvt_kernel<<<dim3((CH * CH + 255) / 256), 256, 0, stream>>>(out_w, wob, CH * CH);
    // 1. LN + transpose -> xn^T (single x read)
    ln_transpose_kernel<<<dim3(NPOS / 32, BATCH), 256, 0, stream>>>(x, norm_g, xnt);
    // 2. QKV projection: persistent MFMA, 256 blocks x 6 tiles
    mfma_gemm256p_kernel<6><<<dim3(256), 512, 0, stream>>>(
        wqb, xnt, (size_t)NPOS * CH, qkv, (size_t)OQKV * NPOS, nullptr);
    // 3. k softmax stats (no materialized normalize)
    k_stats_kernel<<<dim3(DHEAD, NHEAD, BATCH), 256, 0, stream>>>(qkv, kstat);
    // 4. context partials via MFMA (k normalize fused)
    ctx_mfma_kernel<<<dim3(4, NHEAD, BATCH), 256, 0, stream>>>(qkv, kstat, ctx);
    // 5. attention out via MFMA (incl. q softmax) -> v-slot transposed [n][hid]
    attn_out_kernel<<<dim3(16, NHEAD, BATCH), 256, 0, stream>>>(qkv, ctx);
    // 6. out projection + bias: persistent MFMA, 256 blocks x 2 tiles -> k-slot
    mfma_gemm256p_kernel<2><<<dim3(256), 512, 0, stream>>>(
        wob, qkv + (size_t)2 * CH * NPOS, (size_t)OQKV * NPOS,
        qkv + (size_t)CH * NPOS, (size_t)OQKV * NPOS, out_b);
    // 7. final LN -> d_out (overwrites scratch; scratch dead by now)
    ln_final_kernel<<<dim3(NPOS / 32, BATCH), 256, 0, stream>>>(qkv, out_norm_g, outp);
}

// Round 6
// 569.742 us; speedup vs baseline: 1.7095x; 1.0084x over previous
//
#include <hip/hip_runtime.h>
#include <hip/hip_bf16.h>
#include <cstddef>

typedef __hip_bfloat16 bf16;
typedef __attribute__((ext_vector_type(8))) short s16x8;
typedef __attribute__((ext_vector_type(4))) short s16x4;
typedef __attribute__((ext_vector_type(4))) float f32x4;

static constexpr int BATCH = 16;
static constexpr int CH    = 512;    // DIM
static constexpr int NPOS  = 4096;   // h*w
static constexpr int OQKV  = 1536;   // 3*HID
static constexpr int NHEAD = 8;
static constexpr int DHEAD = 64;
#define EPSF 1e-5f
#define QSCALE 0.125f

__device__ __forceinline__ float b2f(bf16 v){ return __bfloat162float(v); }
__device__ __forceinline__ bf16  f2b(float v){ return __float2bfloat16(v); }
__device__ __forceinline__ unsigned short f2bbits(float v){
    bf16 t = __float2bfloat16(v);
    return *reinterpret_cast<unsigned short*>(&t);
}
__device__ __forceinline__ float s2f(short s){
    union { unsigned u; float f; } c; c.u = ((unsigned)(unsigned short)s) << 16; return c.f;
}
// slot index (16B units) of operand[row][kchunk cb] in the XOR-micro-tiled
// LDS layout: [rowgroup=row>>3][rowlow=row&7][kcfield = cb ^ (row&7)]
__device__ __forceinline__ int swzslot(int row, int cb) {
    return ((row >> 3) << 6) + ((row & 7) << 3) + (cb ^ (row & 7));
}

// ---------------- K0: fp32 -> bf16 convert (weights) ----------------------
__global__ __launch_bounds__(256) void cvt_kernel(
    const float* __restrict__ in, bf16* __restrict__ out, int n)
{
    int i = blockIdx.x * 256 + threadIdx.x;
    if (i < n) out[i] = f2b(in[i]);
}

// ---------------- K1: fused chan-LN + transpose, SINGLE x read ------------
__global__ __launch_bounds__(256) void ln_transpose_kernel(
    const float* __restrict__ x, const float* __restrict__ g, bf16* __restrict__ xt)
{
    __shared__ unsigned short st[512][35];   // [c][p]
    __shared__ float red[16][32];
    __shared__ float sm[32], sr[32];
    __shared__ float gl[512];
    int tid = threadIdx.x;
    int p0 = blockIdx.x * 32, b = blockIdx.y;
    int pl = tid & 31, gq = tid >> 5;        // 8 channel-groups
    const float* xb = x + (size_t)b * CH * NPOS + p0;
    for (int i = tid; i < 512; i += 256) gl[i] = g[i];
    float s = 0.f, s2 = 0.f;
    #pragma unroll
    for (int it = 0; it < 64; it++) {
        int c = it * 8 + gq;
        float v = xb[(size_t)c * NPOS + pl];
        s += v; s2 += v * v;
        st[c][pl] = f2bbits(v);
    }
    red[gq][pl] = s; red[8 + gq][pl] = s2;
    __syncthreads();
    if (tid < 32) {
        float ts = 0.f, ts2 = 0.f;
        #pragma unroll
        for (int u = 0; u < 8; u++) { ts += red[u][tid]; ts2 += red[8 + u][tid]; }
        float m   = ts * (1.f / CH);
        float var = ts2 * (1.f / CH) - m * m;
        sm[tid] = m;
        sr[tid] = rsqrtf(var + EPSF);
    }
    __syncthreads();
    int r = tid >> 3, cl = tid & 7;
    float m = sm[r], rs = sr[r];
    bf16* orow = xt + ((size_t)b * NPOS + p0 + r) * CH;
    #pragma unroll
    for (int i2 = 0; i2 < 8; i2++) {
        s16x8 pk;
        #pragma unroll
        for (int u = 0; u < 8; u++) {
            int c = i2 * 64 + cl * 8 + u;
            float v = s2f((short)st[c][r]);
            pk[u] = (short)f2bbits((v - m) * rs * gl[c]);
        }
        *(s16x8*)(orow + i2 * 64 + cl * 8) = pk;
    }
}

// ---------------- K2/K7: persistent MFMA bf16 GEMM, 256x256 tiles ---------
// R6 schedule: ALL 8 stage instrs for step s+1 issue at s.q0 (full-step
// flight time ~7K cy >> HBM latency), counted vmcnt(8); only TWO barriers
// per step (post-vmcnt + end-of-step) -- the minimum the staging/read
// dependences require. Interior phases run barrier-free so the 2 waves/SIMD
// drift and co-schedule MFMA against ds_read.
template<int NOB>
__global__ __launch_bounds__(512, 2) void mfma_gemm256p_kernel(
    const bf16* __restrict__ A, const bf16* __restrict__ B, size_t Bbatch,
    bf16* __restrict__ C, size_t Cbatch, const float* __restrict__ bias)
{
    __shared__ alignas(16) short As[2][16384];
    __shared__ alignas(16) short Bs[2][16384];
    constexpr int NSTEPS = NOB * 8;
    int tid  = threadIdx.x;
    int lane = tid & 63, w = tid >> 6;
    int wr = w >> 2, wc = w & 3;
    int bid = blockIdx.x;

    f32x4 acc[8][4];
    #pragma unroll
    for (int i = 0; i < 8; i++)
        #pragma unroll
        for (int j = 0; j < 4; j++) acc[i][j] = f32x4{0.f, 0.f, 0.f, 0.f};

    auto decode = [&](int step, const bf16*& Ab, const bf16*& Bp,
                      int& oT, int& pT, int& b) {
        int L  = bid * NOB + (step >> 3);
        pT     = (L & 15) * 256;
        int rem = L >> 4;
        int oB  = rem % NOB;
        b       = rem / NOB;
        oT      = oB * 256;
        Ab = A + (size_t)oT * 512;
        Bp = B + (size_t)b * Bbatch + (size_t)pT * 512;
    };

    // stage quarter q of step's 256x64 K-tile (A and B) into buffer d.
    // slot s = q*512+tid: rg=s>>6, rl=(s>>3)&7, kcf=s&7; content =
    // operand[rg*8+rl][kcf ^ rl]  (XOR involution, rule #21 both-sides).
    auto stageQ = [&](int d, const bf16* Ab, const bf16* Bp, int kT, int q) {
        int s   = q * 512 + tid;
        int rl  = (s >> 3) & 7;
        int row = ((s >> 6) << 3) + rl;
        int kcs = (s & 7) ^ rl;              // pre-swizzled source kchunk
        const bf16* ga = Ab + (size_t)row * 512 + kT + kcs * 8;
        const bf16* gb = Bp + (size_t)row * 512 + kT + kcs * 8;
        int sbase = q * 512 + w * 64;        // wave-uniform; lane l -> slot sbase+l
        __builtin_amdgcn_global_load_lds(
            (const __attribute__((address_space(1))) void*)ga,
            (__attribute__((address_space(3))) void*)(&As[d][(size_t)sbase * 8]), 16, 0, 0);
        __builtin_amdgcn_global_load_lds(
            (const __attribute__((address_space(1))) void*)gb,
            (__attribute__((address_space(3))) void*)(&Bs[d][(size_t)sbase * 8]), 16, 0, 0);
    };

    {
        const bf16 *A0, *B0; int o_, p_, b_;
        decode(0, A0, B0, o_, p_, b_);
        #pragma unroll
        for (int q = 0; q < 4; ++q) stageQ(0, A0, B0, 0, q);
    }

    #pragma unroll 1
    for (int s = 0; s < NSTEPS; ++s) {
        int cur = s & 1;
        bool hn = (s + 1) < NSTEPS;
        if (hn) {
            const bf16 *An, *Bn; int o_, p_, b_;
            decode(s + 1, An, Bn, o_, p_, b_);
            int ktn = ((s + 1) & 7) * 64;
            #pragma unroll
            for (int q = 0; q < 4; ++q) stageQ(cur ^ 1, An, Bn, ktn, q);
            // drain step-s loads (issued a full step ago); keep the 8 new in flight
            asm volatile("s_waitcnt vmcnt(8)" ::: "memory");
        } else {
            asm volatile("s_waitcnt vmcnt(0)" ::: "memory");
        }
        __builtin_amdgcn_s_barrier();        // all waves' loads to cur landed
        asm volatile("" ::: "memory");       // keep ds_reads below the barrier

        const s16x8* Av = (const s16x8*)As[cur];
        const s16x8* Bv = (const s16x8*)Bs[cur];
        s16x8 bfr[4];
        #pragma unroll
        for (int q = 0; q < 4; ++q) {
            const int ih = q & 1;
            int cbase = (q >> 1) * 4 + (lane >> 4);
            s16x8 af[4];
            #pragma unroll
            for (int i = 0; i < 4; i++)
                af[i] = Av[swzslot(wr * 128 + (ih * 4 + i) * 16 + (lane & 15), cbase)];
            if (ih == 0) {
                #pragma unroll
                for (int j = 0; j < 4; j++)
                    bfr[j] = Bv[swzslot(wc * 64 + j * 16 + (lane & 15), cbase)];
            }
            asm volatile("s_waitcnt lgkmcnt(0)" ::: "memory");
            __builtin_amdgcn_sched_barrier(0);   // rule #18: pin MFMA below the wait
            __builtin_amdgcn_s_setprio(1);
            #pragma unroll
            for (int i = 0; i < 4; i++)
                #pragma unroll
                for (int j = 0; j < 4; j++)
                    acc[ih * 4 + i][j] = __builtin_amdgcn_mfma_f32_16x16x32_bf16(
                        af[i], bfr[j], acc[ih * 4 + i][j], 0, 0, 0);
            __builtin_amdgcn_s_setprio(0);
            __builtin_amdgcn_sched_barrier(0);
        }
        asm volatile("" ::: "memory");
        __builtin_amdgcn_s_barrier();        // reads of cur done before overwrite

        if ((s & 7) == 7) {
            const bf16 *d1, *d2; int oT, pT, b;
            decode(s, d1, d2, oT, pT, b);
            bf16* Cb = C + (size_t)b * Cbatch;
            #pragma unroll
            for (int i = 0; i < 8; i++) {
                #pragma unroll
                for (int r = 0; r < 4; r++) {
                    int o = oT + wr * 128 + i * 16 + (lane >> 4) * 4 + r;
                    float bv = bias ? bias[o] : 0.f;
                    #pragma unroll
                    for (int j = 0; j < 4; j++) {
                        int p = pT + wc * 64 + j * 16 + (lane & 15);
                        Cb[(size_t)o * NPOS + p] = f2b(acc[i][j][r] + bv);
                    }
                }
            }
            #pragma unroll
            for (int i = 0; i < 8; i++)
                #pragma unroll
                for (int j = 0; j < 4; j++) acc[i][j] = f32x4{0.f, 0.f, 0.f, 0.f};
        }
    }
}

// ---------------- K4: k softmax STATS only (max, 1/sum) over n ------------
__global__ __launch_bounds__(256) void k_stats_kernel(
    const bf16* __restrict__ qkv, float2* __restrict__ kstat)
{
    int d = blockIdx.x, m = blockIdx.y, b = blockIdx.z;
    const bf16* row = qkv + ((size_t)b * OQKV + CH + m * DHEAD + d) * NPOS;
    __shared__ float red[256];
    int tid = threadIdx.x;
    s16x8 v0 = *(const s16x8*)(row + tid * 16);
    s16x8 v1 = *(const s16x8*)(row + tid * 16 + 8);
    float r[16];
    #pragma unroll
    for (int u = 0; u < 8; u++) { r[u] = s2f(v0[u]); r[8 + u] = s2f(v1[u]); }
    float mx = -1e30f;
    #pragma unroll
    for (int u = 0; u < 16; u++) mx = fmaxf(mx, r[u]);
    red[tid] = mx; __syncthreads();
    for (int s = 128; s > 0; s >>= 1) { if (tid < s) red[tid] = fmaxf(red[tid], red[tid + s]); __syncthreads(); }
    mx = red[0]; __syncthreads();
    float sum = 0.f;
    #pragma unroll
    for (int u = 0; u < 16; u++) sum += __expf(r[u] - mx);
    red[tid] = sum; __syncthreads();
    for (int s = 128; s > 0; s >>= 1) { if (tid < s) red[tid] += red[tid + s]; __syncthreads(); }
    if (tid == 0) {
        float2 st; st.x = mx; st.y = 1.f / red[0];
        kstat[((size_t)b * NHEAD + m) * DHEAD + d] = st;
    }
}

// ---------------- K5: context partials via MFMA ---------------------------
__global__ __launch_bounds__(256) void ctx_mfma_kernel(
    const bf16* __restrict__ qkv, const float2* __restrict__ kstat,
    float* __restrict__ ctx)
{
    int tid = threadIdx.x;
    int lane = tid & 63, w = tid >> 6;
    int lr = lane & 15, lc = lane >> 4;
    int split = blockIdx.x, m = blockIdx.y, b = blockIdx.z;
    int nBase = split * (NPOS / 4);
    int iBand = w * 16;
    const bf16* kb = qkv + ((size_t)b * OQKV + CH     + m * DHEAD) * NPOS;
    const bf16* vb = qkv + ((size_t)b * OQKV + 2 * CH + m * DHEAD) * NPOS;
    float2 st = kstat[((size_t)b * NHEAD + m) * DHEAD + iBand + lr];
    const float mx = st.x, inv = st.y;
    const bf16* ka  = kb + (size_t)(iBand + lr) * NPOS + nBase + lc * 8;
    const bf16* va0 = vb + (size_t)(lr)      * NPOS + nBase + lc * 8;
    const bf16* va1 = va0 + (size_t)16 * NPOS;
    const bf16* va2 = va0 + (size_t)32 * NPOS;
    const bf16* va3 = va0 + (size_t)48 * NPOS;
    f32x4 acc0 = {0.f,0.f,0.f,0.f}, acc1 = {0.f,0.f,0.f,0.f};
    f32x4 acc2 = {0.f,0.f,0.f,0.f}, acc3 = {0.f,0.f,0.f,0.f};
    #pragma unroll 4
    for (int ch = 0; ch < 32; ++ch) {
        int off = ch * 32;
        s16x8 kraw = *(const s16x8*)(ka  + off);
        s16x8 b0   = *(const s16x8*)(va0 + off);
        s16x8 b1   = *(const s16x8*)(va1 + off);
        s16x8 b2   = *(const s16x8*)(va2 + off);
        s16x8 b3   = *(const s16x8*)(va3 + off);
        s16x8 af;
        #pragma unroll
        for (int u = 0; u < 8; u++)
            af[u] = (short)f2bbits(__expf(s2f(kraw[u]) - mx) * inv);
        acc0 = __builtin_amdgcn_mfma_f32_16x16x32_bf16(af, b0, acc0, 0, 0, 0);
        acc1 = __builtin_amdgcn_mfma_f32_16x16x32_bf16(af, b1, acc1, 0, 0, 0);
        acc2 = __builtin_amdgcn_mfma_f32_16x16x32_bf16(af, b2, acc2, 0, 0, 0);
        acc3 = __builtin_amdgcn_mfma_f32_16x16x32_bf16(af, b3, acc3, 0, 0, 0);
    }
    float* cb = ctx + ((size_t)split * BATCH * NHEAD + b * NHEAD + m) * (DHEAD * DHEAD);
    #pragma unroll
    for (int r = 0; r < 4; r++) {
        int i = iBand + lc * 4 + r;        // D: row=(lane>>4)*4+r, col=lane&15
        cb[i * 64 +  0 + lr] = acc0[r];
        cb[i * 64 + 16 + lr] = acc1[r];
        cb[i * 64 + 32 + lr] = acc2[r];
        cb[i * 64 + 48 + lr] = acc3[r];
    }
}

// ---------------- K6: fused q-softmax + O^T via MFMA -> v-slot [n][hid] ---
__global__ __launch_bounds__(256) void attn_out_kernel(
    bf16* __restrict__ qkv, const float* __restrict__ ctx)
{
    __shared__ unsigned short qt[256 * 64];   // swizzled [n][i], 32 KB
    __shared__ unsigned short cst[64 * 64];   // swizzled [j][i], 8 KB
    int tid = threadIdx.x;
    int nT = blockIdx.x * 256;
    int m = blockIdx.y, b = blockIdx.z;
    size_t cbase = (size_t)(b * NHEAD + m) * (DHEAD * DHEAD);
    constexpr size_t CSPLIT = (size_t)BATCH * NHEAD * DHEAD * DHEAD;
    {
        int i = tid >> 2, j0 = (tid & 3) * 16;   // fixed i, 16 consecutive j
        #pragma unroll
        for (int e = 0; e < 16; e++) {
            int j = j0 + e;
            size_t l = cbase + (size_t)i * 64 + j;
            float v = ctx[l] + ctx[CSPLIT + l] + ctx[2 * CSPLIT + l] + ctx[3 * CSPLIT + l];
            cst[j * 64 + (((i >> 3) ^ (j & 7)) * 8) + (i & 7)] = f2bbits(v);
        }
    }
    const bf16* q = qkv + ((size_t)b * OQKV + m * DHEAD) * NPOS + nT + tid;
    float qr[DHEAD];
    float mx = -1e30f;
    #pragma unroll
    for (int i = 0; i < DHEAD; i++) { qr[i] = b2f(q[(size_t)i * NPOS]); mx = fmaxf(mx, qr[i]); }
    float s = 0.f;
    #pragma unroll
    for (int i = 0; i < DHEAD; i++) { qr[i] = __expf(qr[i] - mx); s += qr[i]; }
    float inv = QSCALE / s;
    #pragma unroll
    for (int s8 = 0; s8 < 8; s8++) {
        s16x8 pk;
        #pragma unroll
        for (int u = 0; u < 8; u++) pk[u] = (short)f2bbits(qr[s8 * 8 + u] * inv);
        *(s16x8*)&qt[tid * 64 + ((s8 ^ (tid & 7)) * 8)] = pk;
    }
    __syncthreads();
    int lane = tid & 63, w = tid >> 6, lr = lane & 15, lc = lane >> 4;
    s16x8 bf2[4][2];
    #pragma unroll
    for (int jb = 0; jb < 4; jb++)
        #pragma unroll
        for (int kc = 0; kc < 2; kc++)
            bf2[jb][kc] = *(const s16x8*)&cst[(jb * 16 + lr) * 64 + (((kc * 4 + lc) ^ (lr & 7)) * 8)];
    bf16* ovt = qkv + ((size_t)b * OQKV + 2 * CH) * NPOS;
    #pragma unroll
    for (int sub = 0; sub < 4; ++sub) {
        int nl = w * 64 + sub * 16 + lr;      // A row (local n)
        s16x8 a0 = *(const s16x8*)&qt[nl * 64 + (((0 + lc) ^ (nl & 7)) * 8)];
        s16x8 a1 = *(const s16x8*)&qt[nl * 64 + (((4 + lc) ^ (nl & 7)) * 8)];
        #pragma unroll
        for (int jb = 0; jb < 4; jb++) {
            f32x4 acc = f32x4{0.f, 0.f, 0.f, 0.f};
            acc = __builtin_amdgcn_mfma_f32_16x16x32_bf16(a0, bf2[jb][0], acc, 0, 0, 0);
            acc = __builtin_amdgcn_mfma_f32_16x16x32_bf16(a1, bf2[jb][1], acc, 0, 0, 0);
            #pragma unroll
            for (int r = 0; r < 4; r++) {
                int nrow = nT + w * 64 + sub * 16 + lc * 4 + r;   // D row
                ovt[(size_t)nrow * CH + m * DHEAD + jb * 16 + lr] = f2b(acc[r]);
            }
        }
    }
}

// ---------------- K8: final channel-LN, SINGLE read (values in registers) -
__global__ __launch_bounds__(256) void ln_final_kernel(
    const bf16* __restrict__ qkv, const float* __restrict__ g2, float* __restrict__ out)
{
    int tid = threadIdx.x;
    int p0 = blockIdx.x * 32, b = blockIdx.y;
    int pl = tid & 31, gq = tid >> 5;
    const bf16* xp = qkv + ((size_t)b * OQKV + CH) * NPOS + p0 + pl;
    float vals[64];
    float s = 0.f, s2 = 0.f;
    #pragma unroll
    for (int it = 0; it < 64; it++) {
        int c = it * 8 + gq;
        float v = b2f(xp[(size_t)c * NPOS]);
        vals[it] = v; s += v; s2 += v * v;
    }
    __shared__ float red[16][32];
    __shared__ float sm[32], sr[32];
    red[gq][pl] = s; red[8 + gq][pl] = s2;
    __syncthreads();
    if (tid < 32) {
        float ts = 0.f, ts2 = 0.f;
        #pragma unroll
        for (int u = 0; u < 8; u++) { ts += red[u][tid]; ts2 += red[8 + u][tid]; }
        float m   = ts * (1.f / CH);
        float var = ts2 * (1.f / CH) - m * m;
        sm[tid] = m;
        sr[tid] = rsqrtf(var + EPSF);
    }
    __syncthreads();
    float m = sm[pl], rs = sr[pl];
    float* op = out + (size_t)b * CH * NPOS + p0 + pl;
    #pragma unroll
    for (int it = 0; it < 64; it++) {
        int c = it * 8 + gq;
        op[(size_t)c * NPOS] = (vals[it] - m) * rs * g2[c];
    }
}

extern "C" void kernel_launch(void* const* d_in, const int* in_sizes, int n_in,
                              void* d_out, int out_size, void* d_ws, size_t ws_size,
                              hipStream_t stream)
{
    const float* x          = (const float*)d_in[0];
    const float* norm_g     = (const float*)d_in[1];
    const float* qkv_w      = (const float*)d_in[2];
    const float* out_w      = (const float*)d_in[3];
    const float* out_b      = (const float*)d_in[4];
    const float* out_norm_g = (const float*)d_in[5];
    float* outp = (float*)d_out;

    char* ws = (char*)d_ws;
    bf16*  qkv = (bf16*)ws;                                  // 201,326,592 B
    bf16*  wqb = (bf16*)(ws + (size_t)201326592);            // 1536*512 bf16
    bf16*  wob = wqb + (size_t)OQKV * CH;                    // 512*512 bf16
    float* ctx = (float*)(wob + (size_t)CH * CH);            // 4*16*8*64*64 f32
    bf16*  xnt = (bf16*)d_out;                               // xn^T scratch (first 64 MB of out)
    float2* kstat = (float2*)((char*)d_out + (size_t)67108864); // 64 KB scratch past xnt

    // 0. weight conversion
    cvt_kernel<<<dim3((OQKV * CH + 255) / 256), 256, 0, stream>>>(qkv_w, wqb, OQKV * CH);
    cvt_kernel<<<dim3((CH * CH + 255) / 256), 256, 0, stream>>>(out_w, wob, CH * CH);
    // 1. LN + transpose -> xn^T (single x read)
    ln_transpose_kernel<<<dim3(NPOS / 32, BATCH), 256, 0, stream>>>(x, norm_g, xnt);
    // 2. QKV projection: persistent MFMA, 256 blocks x 6 tiles
    mfma_gemm256p_kernel<6><<<dim3(256), 512, 0, stream>>>(
        wqb, xnt, (size_t)NPOS * CH, qkv, (size_t)OQKV * NPOS, nullptr);
    // 3. k softmax stats (no materialized normalize)
    k_stats_kernel<<<dim3(DHEAD, NHEAD, BATCH), 256, 0, stream>>>(qkv, kstat);
    // 4. context partials via MFMA (k normalize fused)
    ctx_mfma_kernel<<<dim3(4, NHEAD, BATCH), 256, 0, stream>>>(qkv, kstat, ctx);
    // 5. attention out via MFMA (incl. q softmax) -> v-slot transposed [n][hid]
    attn_out_kernel<<<dim3(16, NHEAD, BATCH), 256, 0, stream>>>(qkv, ctx);
    // 6. out projection + bias: persistent MFMA, 256 blocks x 2 tiles -> k-slot
    mfma_gemm256p_kernel<2><<<dim3(256), 512, 0, stream>>>(
        wob, qkv + (size_t)2 * CH * NPOS, (size_t)OQKV * NPOS,
        qkv + (size_t)CH * NPOS, (size_t)OQKV * NPOS, out_b);
    // 7. final LN -> d_out (overwrites scratch; scratch dead by now)
    ln_final_kernel<<<dim3(NPOS / 32, BATCH), 256, 0, stream>>>(qkv, out_norm_g, outp);
}